// Round 1
// baseline (571.872 us; speedup 1.0000x reference)
//
#include <hip/hip_runtime.h>
#include <math.h>

#define B_   2
#define N_   768
#define CN_  384
#define H_   12
#define C_   16
#define PQ_  4
#define PV_  8
#define TI   32
#define INF_ 100000.0f
#define EPS_ 1e-7f

// ---------------- workspace layout (floats) ----------------
// Q  [B][H][N][C]        294912   (pre-scaled by 1/sqrt(48))
// K  [B][H][N][C]        294912
// V  [B][H][N][C]        294912
// QP [B][H][N][12]       221184   (rotated+translated q points, flattened p*3+x)
// KP [B][H][N][12]       221184
// VP [B][H][N][24]       442368
// K2 [B][H][N]           18432    (sum over k-points of |kp|^2)
// O  [B][N][H*C]         294912
// OP [B][N][H*PV*3]      442368
#define OFF_Q  0
#define OFF_K  294912
#define OFF_V  589824
#define OFF_QP 884736
#define OFF_KP 1105920
#define OFF_VP 1327104
#define OFF_K2 1769472
#define OFF_O  1787904
#define OFF_OP 2082816

// ============================================================
// Kernel A: fused projections + point transform, one block per (b,n)
// ============================================================
__global__ __launch_bounds__(256) void proj_kernel(
    const float* __restrict__ s, const float* __restrict__ rot, const float* __restrict__ trans,
    const float* __restrict__ w_q,  const float* __restrict__ b_q,
    const float* __restrict__ w_kv, const float* __restrict__ b_kv,
    const float* __restrict__ w_qp, const float* __restrict__ b_qp,
    const float* __restrict__ w_kvp,const float* __restrict__ b_kvp,
    float* __restrict__ Qg, float* __restrict__ Kg, float* __restrict__ Vg,
    float* __restrict__ QPg, float* __restrict__ KPg, float* __restrict__ VPg,
    float* __restrict__ K2g)
{
    __shared__ float srow[CN_];
    __shared__ float proj[1152];
    __shared__ float rt[12];     // rot(9) + trans(3)
    __shared__ float kp2[48];    // per (h, kp-point) |kp|^2

    const int bn = blockIdx.x;
    const int t  = threadIdx.x;

    const float* srp = s + bn * CN_;
    for (int k = t; k < CN_; k += 256) srow[k] = srp[k];
    if (t < 9) rt[t]   = rot[bn * 9 + t];
    if (t < 3) rt[9+t] = trans[bn * 3 + t];
    __syncthreads();

    // fused GEMV: 1152 output columns, K=384
    for (int col = t; col < 1152; col += 256) {
        const float* wr; float bias;
        if (col < 192)      { wr = w_q   + col * CN_;        bias = b_q[col]; }
        else if (col < 576) { wr = w_kv  + (col-192) * CN_;  bias = b_kv[col-192]; }
        else if (col < 720) { wr = w_qp  + (col-576) * CN_;  bias = b_qp[col-576]; }
        else                { wr = w_kvp + (col-720) * CN_;  bias = b_kvp[col-720]; }
        const float4* w4 = (const float4*)wr;
        const float4* s4 = (const float4*)srow;
        float acc = 0.f;
        #pragma unroll 8
        for (int k = 0; k < CN_/4; ++k) {
            float4 a = s4[k], w = w4[k];
            acc += a.x*w.x + a.y*w.y + a.z*w.z + a.w*w.w;
        }
        proj[col] = acc + bias;
    }
    __syncthreads();

    const int b = bn / N_, n = bn % N_;
    const float qk_scale = rsqrtf(48.f);

    // q (scaled)
    if (t < 192) {
        int h = t >> 4, c = t & 15;
        Qg[((b*H_ + h)*N_ + n)*C_ + c] = proj[t] * qk_scale;
    }
    // k, v
    for (int d = t; d < 384; d += 256) {
        int h = d >> 5, r = d & 31;
        float val = proj[192 + d];
        if (r < 16) Kg[((b*H_ + h)*N_ + n)*C_ + r]        = val;
        else        Vg[((b*H_ + h)*N_ + n)*C_ + (r - 16)] = val;
    }
    // q points: 48 of them; raw coord y at proj[576 + y*48 + h*4 + p]
    if (t < 48) {
        int h = t >> 2, p = t & 3;
        float r0 = proj[576 + 0*48 + h*4 + p];
        float r1 = proj[576 + 1*48 + h*4 + p];
        float r2 = proj[576 + 2*48 + h*4 + p];
        #pragma unroll
        for (int x = 0; x < 3; ++x) {
            float o = rt[x*3+0]*r0 + rt[x*3+1]*r1 + rt[x*3+2]*r2 + rt[9+x];
            QPg[((b*H_ + h)*N_ + n)*12 + p*3 + x] = o;
        }
    }
    // kv points: 144 of them; raw coord y at proj[720 + y*144 + h*12 + pp]
    if (t >= 64 && t < 208) {
        int tt = t - 64;
        int h = tt / 12, pp = tt % 12;
        float r0 = proj[720 + 0*144 + h*12 + pp];
        float r1 = proj[720 + 1*144 + h*12 + pp];
        float r2 = proj[720 + 2*144 + h*12 + pp];
        float o0 = rt[0]*r0 + rt[1]*r1 + rt[2]*r2 + rt[9];
        float o1 = rt[3]*r0 + rt[4]*r1 + rt[5]*r2 + rt[10];
        float o2 = rt[6]*r0 + rt[7]*r1 + rt[8]*r2 + rt[11];
        if (pp < 4) {
            float* kp = KPg + ((b*H_ + h)*N_ + n)*12 + pp*3;
            kp[0] = o0; kp[1] = o1; kp[2] = o2;
            kp2[h*4 + pp] = o0*o0 + o1*o1 + o2*o2;
        } else {
            float* vp = VPg + ((b*H_ + h)*N_ + n)*24 + (pp-4)*3;
            vp[0] = o0; vp[1] = o1; vp[2] = o2;
        }
    }
    __syncthreads();
    if (t < 12) {
        K2g[(b*H_ + t)*N_ + n] = kp2[t*4] + kp2[t*4+1] + kp2[t*4+2] + kp2[t*4+3];
    }
}

// ============================================================
// Kernel B: flash-style attention, one block per (b, h, i-tile of 32)
// logit(i,j) = q_s[i]·k[j] + (hw*qp[i])·kp[j] - 0.5*hw*K2[j] + INF*(mask-1)
// (the -0.5*hw*Q2[i] term is constant per row -> cancels in softmax)
// ============================================================
__global__ __launch_bounds__(256) void attn_kernel(
    const float* __restrict__ Qg, const float* __restrict__ Kg, const float* __restrict__ Vg,
    const float* __restrict__ QPg, const float* __restrict__ KPg, const float* __restrict__ VPg,
    const float* __restrict__ K2g, const float* __restrict__ head_weights,
    const float* __restrict__ pair_mask,
    float* __restrict__ Og, float* __restrict__ OPg)
{
    __shared__ float qbuf[TI][28];
    __shared__ float kbuf[TI][28];
    __shared__ float vbuf[TI][40];
    __shared__ float kc[TI];

    const int blk = blockIdx.x;
    const int it  = blk % (N_ / TI);
    const int bh  = blk / (N_ / TI);
    const int h   = bh % H_;
    const int b   = bh / H_;
    const int i0  = it * TI;
    const int t   = threadIdx.x;
    const int irow = t >> 3;   // 0..31
    const int jg   = t & 7;    // 0..7
    const int d0   = jg * 5;   // my 5 output dims
    const int lane = t & 63;
    const int lane_base = lane & 56;

    float hwv = head_weights[h];
    float sp  = (hwv > 20.f) ? hwv : log1pf(expf(hwv));
    const float hw = sp * 0.13608276348795434f;   // sqrt(1/54)

    const long baseQ  = (long)((b*H_ + h)*N_) * C_;
    const long baseQP = (long)((b*H_ + h)*N_) * 12;
    const long baseVP = (long)((b*H_ + h)*N_) * 24;
    const long baseK2 = (long)((b*H_ + h)*N_);

    // stage q side (q pre-scaled; fold hw into q-points)
    for (int d = t; d < TI*16; d += 256) {
        int i = d >> 4, c = d & 15;
        qbuf[i][c] = Qg[baseQ + (long)(i0 + i)*C_ + c];
    }
    for (int d = t; d < TI*12; d += 256) {
        int i = d / 12, c = d % 12;
        qbuf[i][16 + c] = QPg[baseQP + (long)(i0 + i)*12 + c] * hw;
    }
    __syncthreads();

    float qr[28];
    #pragma unroll
    for (int c = 0; c < 28; ++c) qr[c] = qbuf[irow][c];

    float m = -1e30f, l = 0.f;
    float acc[5] = {0.f, 0.f, 0.f, 0.f, 0.f};
    const float* maskrow = pair_mask + (long)(b*N_ + (i0 + irow)) * N_;

    for (int jt = 0; jt < N_/TI; ++jt) {
        const int j0 = jt * TI;
        __syncthreads();   // protect kbuf/vbuf from previous-iteration readers
        for (int d = t; d < TI*16; d += 256) {
            int j = d >> 4, c = d & 15;
            kbuf[j][c] = Kg[baseQ + (long)(j0 + j)*C_ + c];
            vbuf[j][c] = Vg[baseQ + (long)(j0 + j)*C_ + c];
        }
        for (int d = t; d < TI*12; d += 256) {
            int j = d / 12, c = d % 12;
            kbuf[j][16 + c] = KPg[baseQP + (long)(j0 + j)*12 + c];
        }
        for (int d = t; d < TI*24; d += 256) {
            int j = d / 24, c = d % 24;
            vbuf[j][16 + c] = VPg[baseVP + (long)(j0 + j)*24 + c];
        }
        if (t < TI) kc[t] = -0.5f * hw * K2g[baseK2 + j0 + t];
        __syncthreads();

        float p[4];
        float mloc = -1e30f;
        #pragma unroll
        for (int q = 0; q < 4; ++q) {
            int j = jg + 8*q;
            float sv = kc[j];
            #pragma unroll
            for (int c = 0; c < 28; ++c) sv += qr[c] * kbuf[j][c];
            sv += INF_ * (maskrow[j0 + j] - 1.f);
            p[q] = sv;
            mloc = fmaxf(mloc, sv);
        }
        // row-reduce over the 8 lanes of this row
        #pragma unroll
        for (int w = 1; w < 8; w <<= 1) mloc = fmaxf(mloc, __shfl_xor(mloc, w, 64));
        float newm = fmaxf(m, mloc);
        float scale = __expf(m - newm);
        float psum = 0.f;
        #pragma unroll
        for (int q = 0; q < 4; ++q) { p[q] = __expf(p[q] - newm); psum += p[q]; }
        #pragma unroll
        for (int w = 1; w < 8; w <<= 1) psum += __shfl_xor(psum, w, 64);
        l = l * scale + psum;
        m = newm;
        #pragma unroll
        for (int d = 0; d < 5; ++d) acc[d] *= scale;
        // broadcast p over the 8 row-lanes, accumulate my 5 dims over all 32 j
        for (int src = 0; src < 8; ++src) {
            #pragma unroll
            for (int q = 0; q < 4; ++q) {
                float pj = __shfl(p[q], lane_base + src, 64);
                int j = src + 8*q;
                #pragma unroll
                for (int d = 0; d < 5; ++d) acc[d] += pj * vbuf[j][d0 + d];
            }
        }
    }

    const float inv = 1.f / l;
    const int n = i0 + irow;
    #pragma unroll
    for (int d = 0; d < 5; ++d) {
        int dim = d0 + d;
        float val = acc[d] * inv;
        if (dim < 16) Og [(long)(b*N_ + n)*(H_*C_)     + h*C_ + dim]
            = val;
        else          OPg[(long)(b*N_ + n)*(H_*PV_*3)  + h*24 + (dim - 16)]
            = val;
    }
}

// ============================================================
// Kernel C: inverse rotation + norms + output GEMV, one block per (b,n)
// ============================================================
__global__ __launch_bounds__(256) void out_kernel(
    const float* __restrict__ Og, const float* __restrict__ OPg,
    const float* __restrict__ rot, const float* __restrict__ trans,
    const float* __restrict__ w_out, const float* __restrict__ b_out,
    float* __restrict__ out)
{
    __shared__ float cat[576];
    __shared__ float rt[12];

    const int bn = blockIdx.x;
    const int t  = threadIdx.x;
    if (t < 9) rt[t]   = rot[bn*9 + t];
    if (t < 3) rt[9+t] = trans[bn*3 + t];
    for (int d = t; d < 192; d += 256) cat[d] = Og[(long)bn*192 + d];
    __syncthreads();

    if (t < 96) {  // one thread per (h, pv) point; t = h*8 + p -> flat offset 3t
        float g0 = OPg[(long)bn*288 + t*3 + 0] - rt[9];
        float g1 = OPg[(long)bn*288 + t*3 + 1] - rt[10];
        float g2 = OPg[(long)bn*288 + t*3 + 2] - rt[11];
        // local[x] = sum_y rot[y][x] * g[y]   (R^T)
        float l0 = rt[0]*g0 + rt[3]*g1 + rt[6]*g2;
        float l1 = rt[1]*g0 + rt[4]*g1 + rt[7]*g2;
        float l2 = rt[2]*g0 + rt[5]*g1 + rt[8]*g2;
        cat[192 + t] = l0;
        cat[288 + t] = l1;
        cat[384 + t] = l2;
        cat[480 + t] = sqrtf(l0*l0 + l1*l1 + l2*l2 + EPS_);
    }
    __syncthreads();

    for (int mcol = t; mcol < 384; mcol += 256) {
        const float4* w4 = (const float4*)(w_out + (long)mcol*576);
        const float4* c4 = (const float4*)cat;
        float acc = 0.f;
        #pragma unroll 8
        for (int k = 0; k < 144; ++k) {
            float4 w = w4[k], c = c4[k];
            acc += c.x*w.x + c.y*w.y + c.z*w.z + c.w*w.w;
        }
        out[(long)bn*384 + mcol] = acc + b_out[mcol];
    }
}

// ============================================================
extern "C" void kernel_launch(void* const* d_in, const int* in_sizes, int n_in,
                              void* d_out, int out_size, void* d_ws, size_t ws_size,
                              hipStream_t stream) {
    const float* s           = (const float*)d_in[0];
    const float* rot         = (const float*)d_in[1];
    const float* trans       = (const float*)d_in[2];
    const float* pair_mask   = (const float*)d_in[3];
    const float* w_q         = (const float*)d_in[4];
    const float* b_q         = (const float*)d_in[5];
    const float* w_kv        = (const float*)d_in[6];
    const float* b_kv        = (const float*)d_in[7];
    const float* w_qp        = (const float*)d_in[8];
    const float* b_qp        = (const float*)d_in[9];
    const float* w_kvp       = (const float*)d_in[10];
    const float* b_kvp       = (const float*)d_in[11];
    const float* head_weights= (const float*)d_in[12];
    const float* w_out       = (const float*)d_in[13];
    const float* b_out       = (const float*)d_in[14];
    float* out = (float*)d_out;
    float* ws  = (float*)d_ws;

    float* Q  = ws + OFF_Q;
    float* K  = ws + OFF_K;
    float* V  = ws + OFF_V;
    float* QP = ws + OFF_QP;
    float* KP = ws + OFF_KP;
    float* VP = ws + OFF_VP;
    float* K2 = ws + OFF_K2;
    float* O  = ws + OFF_O;
    float* OP = ws + OFF_OP;

    proj_kernel<<<B_*N_, 256, 0, stream>>>(s, rot, trans, w_q, b_q, w_kv, b_kv,
                                           w_qp, b_qp, w_kvp, b_kvp,
                                           Q, K, V, QP, KP, VP, K2);
    attn_kernel<<<B_*H_*(N_/TI), 256, 0, stream>>>(Q, K, V, QP, KP, VP, K2,
                                                   head_weights, pair_mask, O, OP);
    out_kernel<<<B_*N_, 256, 0, stream>>>(O, OP, rot, trans, w_out, b_out, out);
}

// Round 2
// 177.806 us; speedup vs baseline: 3.2163x; 3.2163x over previous
//
#include <hip/hip_runtime.h>
#include <math.h>

#define B_   2
#define N_   768
#define CN_  384
#define H_   12
#define TI   32
#define INF_ 100000.0f
#define EPS_ 1e-7f

// ---------------- workspace layout (floats) ----------------
// PROJ  [1536][1152]  raw GEMM out, then packed per-head rows (in-place), later aliased by CAT
// KC    [1536][12]    -0.5*hw*sum|kp|^2
// O     [1536][192]
// OP    [1536][288]
#define OFF_PROJ 0
#define OFF_KC   1769472
#define OFF_O    1787904
#define OFF_OP   2082816
#define OFF_CAT  0

// ============================================================
// fused projection GEMM: proj[1536][1152] = S[1536][384] @ Wcat^T
// 64x64 tile, BK=32, 256 threads, 4x4 micro-tile
// ============================================================
__global__ __launch_bounds__(256) void proj_gemm(
    const float* __restrict__ s,
    const float* __restrict__ w_q,  const float* __restrict__ w_kv,
    const float* __restrict__ w_qp, const float* __restrict__ w_kvp,
    float* __restrict__ proj)
{
    __shared__ float As[32][68];
    __shared__ float Bs[32][68];
    const int t = threadIdx.x;
    const int tile_n = blockIdx.x % 18;
    const int tile_m = blockIdx.x / 18;
    const int m0 = tile_m * 64, n0 = tile_n * 64;
    const int tx = t & 15, ty = t >> 4;

    const float* ap[8]; const float* bp[8];
    int ar[8], ac[8];
    #pragma unroll
    for (int e = 0; e < 8; ++e) {
        int idx = t + e * 256;
        int r = idx >> 5, c = idx & 31;
        ar[e] = r; ac[e] = c;
        ap[e] = s + (long)(m0 + r) * CN_ + c;
        int col = n0 + r;
        const float* wb;
        if (col < 192)      wb = w_q   + (long)col * CN_;
        else if (col < 576) wb = w_kv  + (long)(col - 192) * CN_;
        else if (col < 720) wb = w_qp  + (long)(col - 576) * CN_;
        else                wb = w_kvp + (long)(col - 720) * CN_;
        bp[e] = wb + c;
    }
    float acc[4][4] = {};
    for (int kt = 0; kt < CN_ / 32; ++kt) {
        const int k0 = kt * 32;
        __syncthreads();
        #pragma unroll
        for (int e = 0; e < 8; ++e) {
            As[ac[e]][ar[e]] = ap[e][k0];
            Bs[ac[e]][ar[e]] = bp[e][k0];
        }
        __syncthreads();
        #pragma unroll
        for (int kk = 0; kk < 32; ++kk) {
            float4 a4 = *(const float4*)&As[kk][ty * 4];
            float4 b4 = *(const float4*)&Bs[kk][tx * 4];
            float a[4] = {a4.x, a4.y, a4.z, a4.w};
            float b[4] = {b4.x, b4.y, b4.z, b4.w};
            #pragma unroll
            for (int i = 0; i < 4; ++i)
                #pragma unroll
                for (int j = 0; j < 4; ++j)
                    acc[i][j] += a[i] * b[j];
        }
    }
    #pragma unroll
    for (int i = 0; i < 4; ++i) {
        float4 st = {acc[i][0], acc[i][1], acc[i][2], acc[i][3]};
        *(float4*)(proj + (long)(m0 + ty * 4 + i) * 1152 + n0 + tx * 4) = st;
    }
}

// ============================================================
// pack: bias + rotate/translate points + pre-scales, repack row in-place to
// per-head layout: h*96 + [0:16)q*1/sqrt48 [16:28)qp*hw [28:44)k [44:56)kp [56:72)v [72:96)vp
// also emits kc[bn][h] = -0.5*hw*sum|kp|^2
// ============================================================
__global__ __launch_bounds__(256) void pack_kernel(
    float* __restrict__ proj,
    const float* __restrict__ rot, const float* __restrict__ trans,
    const float* __restrict__ b_q,  const float* __restrict__ b_kv,
    const float* __restrict__ b_qp, const float* __restrict__ b_kvp,
    const float* __restrict__ head_weights,
    float* __restrict__ kc)
{
    __shared__ float raw[1152];
    __shared__ float pk[1152];
    __shared__ float rt[12];
    __shared__ float hws[12];
    const int bn = blockIdx.x;
    const int t  = threadIdx.x;
    float* rowg = proj + (long)bn * 1152;
    for (int d = t; d < 1152; d += 256) {
        float bias = (d < 192) ? b_q[d] : (d < 576) ? b_kv[d - 192]
                   : (d < 720) ? b_qp[d - 576] : b_kvp[d - 720];
        raw[d] = rowg[d] + bias;
    }
    if (t < 9) rt[t]     = rot[bn * 9 + t];
    if (t < 3) rt[9 + t] = trans[bn * 3 + t];
    if (t < 12) {
        float v  = head_weights[t];
        float sp = (v > 20.f) ? v : log1pf(expf(v));
        hws[t] = sp * 0.13608276348795434f;  // softplus * sqrt(1/54)
    }
    __syncthreads();
    for (int slot = t; slot < 1152; slot += 256) {
        int h = slot / 96, o = slot - h * 96;
        float val;
        if (o < 16) {
            val = raw[h * 16 + o] * 0.144337567297406f;  // 1/sqrt(48)
        } else if (o < 28) {
            int c = o - 16, p = c / 3, x = c - p * 3;
            float r0 = raw[576 +      h * 4 + p];
            float r1 = raw[576 + 48 + h * 4 + p];
            float r2 = raw[576 + 96 + h * 4 + p];
            val = (rt[x*3]*r0 + rt[x*3+1]*r1 + rt[x*3+2]*r2 + rt[9+x]) * hws[h];
        } else if (o < 44) {
            val = raw[192 + h * 32 + (o - 28)];
        } else if (o < 56) {
            int c = o - 44, p = c / 3, x = c - p * 3;
            float r0 = raw[720 +       h * 12 + p];
            float r1 = raw[720 + 144 + h * 12 + p];
            float r2 = raw[720 + 288 + h * 12 + p];
            val = rt[x*3]*r0 + rt[x*3+1]*r1 + rt[x*3+2]*r2 + rt[9+x];
        } else if (o < 72) {
            val = raw[192 + h * 32 + 16 + (o - 56)];
        } else {
            int c = o - 72, p = c / 3, x = c - p * 3;
            float r0 = raw[720 +       h * 12 + 4 + p];
            float r1 = raw[720 + 144 + h * 12 + 4 + p];
            float r2 = raw[720 + 288 + h * 12 + 4 + p];
            val = rt[x*3]*r0 + rt[x*3+1]*r1 + rt[x*3+2]*r2 + rt[9+x];
        }
        pk[slot] = val;
    }
    __syncthreads();
    if (t < 12) {
        float s2 = 0.f;
        #pragma unroll
        for (int e = 0; e < 12; ++e) { float v = pk[t * 96 + 44 + e]; s2 += v * v; }
        kc[bn * 12 + t] = -0.5f * hws[t] * s2;
    }
    for (int d = t; d < 288; d += 256)
        ((float4*)rowg)[d] = ((const float4*)pk)[d];
}

// ============================================================
// flash attention over packed rows; one block per (b,h,i-tile of 32)
// ============================================================
__global__ __launch_bounds__(256) void attn_kernel(
    const float* __restrict__ projP, const float* __restrict__ kcg,
    const float* __restrict__ pair_mask,
    float* __restrict__ Og, float* __restrict__ OPg)
{
    __shared__ float qbuf[TI][28];
    __shared__ float kbuf[TI][28];
    __shared__ float vt[40][36];     // transposed V|VP, padded for bank spread
    __shared__ float pbuf[TI][36];
    __shared__ float kc_s[TI];

    const int blk = blockIdx.x;
    const int it  = blk % (N_ / TI);
    const int bh  = blk / (N_ / TI);
    const int h   = bh % H_;
    const int b   = bh / H_;
    const int i0  = it * TI;
    const int t   = threadIdx.x;
    const int irow = t >> 3;
    const int jg   = t & 7;
    const int d0   = jg * 5;
    const long rowbase = (long)b * N_;

    for (int d = t; d < TI * 7; d += 256) {
        int i = d / 7, c = d - i * 7;
        ((float4*)qbuf[i])[c] =
            ((const float4*)(projP + (rowbase + i0 + i) * 1152 + h * 96))[c];
    }
    __syncthreads();
    float4 qr[7];
    #pragma unroll
    for (int c = 0; c < 7; ++c) qr[c] = ((const float4*)qbuf[irow])[c];

    float m = -1e30f, l = 0.f;
    float acc[5] = {0.f, 0.f, 0.f, 0.f, 0.f};
    const float* maskrow = pair_mask + (rowbase + i0 + irow) * N_;

    for (int jt = 0; jt < N_ / TI; ++jt) {
        const int j0 = jt * TI;
        __syncthreads();
        for (int d = t; d < TI * 7; d += 256) {
            int j = d / 7, c = d - j * 7;
            ((float4*)kbuf[j])[c] =
                ((const float4*)(projP + (rowbase + j0 + j) * 1152 + h * 96 + 28))[c];
        }
        for (int d = t; d < TI * 10; d += 256) {
            int j = d / 10, c4 = d - j * 10;
            float4 vv = ((const float4*)(projP + (rowbase + j0 + j) * 1152 + h * 96 + 56))[c4];
            vt[c4 * 4 + 0][j] = vv.x; vt[c4 * 4 + 1][j] = vv.y;
            vt[c4 * 4 + 2][j] = vv.z; vt[c4 * 4 + 3][j] = vv.w;
        }
        if (t < TI) kc_s[t] = kcg[(rowbase + j0 + t) * 12 + h];
        __syncthreads();

        float p[4]; float mloc = -1e30f;
        #pragma unroll
        for (int q = 0; q < 4; ++q) {
            int j = jg + 8 * q;
            const float4* kb = (const float4*)kbuf[j];
            float sv = kc_s[j];
            #pragma unroll
            for (int c = 0; c < 7; ++c) {
                float4 kv = kb[c];
                sv += qr[c].x*kv.x + qr[c].y*kv.y + qr[c].z*kv.z + qr[c].w*kv.w;
            }
            sv += INF_ * (maskrow[j0 + j] - 1.f);
            p[q] = sv;
            mloc = fmaxf(mloc, sv);
        }
        #pragma unroll
        for (int w = 1; w < 8; w <<= 1) mloc = fmaxf(mloc, __shfl_xor(mloc, w, 64));
        float newm = fmaxf(m, mloc);
        float scale = __expf(m - newm);
        float psum = 0.f;
        #pragma unroll
        for (int q = 0; q < 4; ++q) { p[q] = __expf(p[q] - newm); psum += p[q]; }
        #pragma unroll
        for (int w = 1; w < 8; w <<= 1) psum += __shfl_xor(psum, w, 64);
        l = l * scale + psum;
        m = newm;
        #pragma unroll
        for (int q = 0; q < 4; ++q) pbuf[irow][jg + 8 * q] = p[q];
        #pragma unroll
        for (int d = 0; d < 5; ++d) acc[d] *= scale;
        __syncthreads();
        const float4* prow = (const float4*)pbuf[irow];
        #pragma unroll
        for (int d = 0; d < 5; ++d) {
            const float4* vrow = (const float4*)vt[d0 + d];
            float a = 0.f;
            #pragma unroll
            for (int qj = 0; qj < 8; ++qj) {
                float4 pv = prow[qj]; float4 vv = vrow[qj];
                a += pv.x*vv.x + pv.y*vv.y + pv.z*vv.z + pv.w*vv.w;
            }
            acc[d] += a;
        }
    }
    const float inv = 1.f / l;
    const int n = i0 + irow;
    #pragma unroll
    for (int d = 0; d < 5; ++d) {
        int dim = d0 + d;
        float val = acc[d] * inv;
        if (dim < 16) Og [(rowbase + n) * 192 + h * 16 + dim]       = val;
        else          OPg[(rowbase + n) * 288 + h * 24 + (dim - 16)] = val;
    }
}

// ============================================================
// cat build: inverse rotation + norms -> cat[1536][576]
// ============================================================
__global__ __launch_bounds__(128) void cat_kernel(
    const float* __restrict__ Og, const float* __restrict__ OPg,
    const float* __restrict__ rot, const float* __restrict__ trans,
    float* __restrict__ catg)
{
    __shared__ float cat[576];
    __shared__ float rt[12];
    const int bn = blockIdx.x;
    const int t  = threadIdx.x;
    if (t < 9) rt[t]     = rot[bn * 9 + t];
    if (t < 3) rt[9 + t] = trans[bn * 3 + t];
    for (int d = t; d < 192; d += 128) cat[d] = Og[(long)bn * 192 + d];
    __syncthreads();
    if (t < 96) {
        float g0 = OPg[(long)bn * 288 + t * 3 + 0] - rt[9];
        float g1 = OPg[(long)bn * 288 + t * 3 + 1] - rt[10];
        float g2 = OPg[(long)bn * 288 + t * 3 + 2] - rt[11];
        float l0 = rt[0]*g0 + rt[3]*g1 + rt[6]*g2;
        float l1 = rt[1]*g0 + rt[4]*g1 + rt[7]*g2;
        float l2 = rt[2]*g0 + rt[5]*g1 + rt[8]*g2;
        cat[192 + t] = l0;
        cat[288 + t] = l1;
        cat[384 + t] = l2;
        cat[480 + t] = sqrtf(l0*l0 + l1*l1 + l2*l2 + EPS_);
    }
    __syncthreads();
    for (int d = t; d < 144; d += 128)
        ((float4*)(catg + (long)bn * 576))[d] = ((const float4*)cat)[d];
}

// ============================================================
// output GEMM: out[1536][384] = cat[1536][576] @ w_out^T + b_out
// ============================================================
__global__ __launch_bounds__(256) void out_gemm(
    const float* __restrict__ catg, const float* __restrict__ w_out,
    const float* __restrict__ b_out, float* __restrict__ out)
{
    __shared__ float As[32][68];
    __shared__ float Bs[32][68];
    const int t = threadIdx.x;
    const int tile_n = blockIdx.x % 6;
    const int tile_m = blockIdx.x / 6;
    const int m0 = tile_m * 64, n0 = tile_n * 64;
    const int tx = t & 15, ty = t >> 4;

    const float* ap[8]; const float* bp[8];
    int ar[8], ac[8];
    #pragma unroll
    for (int e = 0; e < 8; ++e) {
        int idx = t + e * 256;
        int r = idx >> 5, c = idx & 31;
        ar[e] = r; ac[e] = c;
        ap[e] = catg  + (long)(m0 + r) * 576 + c;
        bp[e] = w_out + (long)(n0 + r) * 576 + c;
    }
    float acc[4][4] = {};
    for (int kt = 0; kt < 18; ++kt) {
        const int k0 = kt * 32;
        __syncthreads();
        #pragma unroll
        for (int e = 0; e < 8; ++e) {
            As[ac[e]][ar[e]] = ap[e][k0];
            Bs[ac[e]][ar[e]] = bp[e][k0];
        }
        __syncthreads();
        #pragma unroll
        for (int kk = 0; kk < 32; ++kk) {
            float4 a4 = *(const float4*)&As[kk][ty * 4];
            float4 b4 = *(const float4*)&Bs[kk][tx * 4];
            float a[4] = {a4.x, a4.y, a4.z, a4.w};
            float b[4] = {b4.x, b4.y, b4.z, b4.w};
            #pragma unroll
            for (int i = 0; i < 4; ++i)
                #pragma unroll
                for (int j = 0; j < 4; ++j)
                    acc[i][j] += a[i] * b[j];
        }
    }
    float4 bb = *(const float4*)(b_out + n0 + tx * 4);
    #pragma unroll
    for (int i = 0; i < 4; ++i) {
        float4 st = {acc[i][0] + bb.x, acc[i][1] + bb.y,
                     acc[i][2] + bb.z, acc[i][3] + bb.w};
        *(float4*)(out + (long)(m0 + ty * 4 + i) * 384 + n0 + tx * 4) = st;
    }
}

// ============================================================
extern "C" void kernel_launch(void* const* d_in, const int* in_sizes, int n_in,
                              void* d_out, int out_size, void* d_ws, size_t ws_size,
                              hipStream_t stream) {
    const float* s            = (const float*)d_in[0];
    const float* rot          = (const float*)d_in[1];
    const float* trans        = (const float*)d_in[2];
    const float* pair_mask    = (const float*)d_in[3];
    const float* w_q          = (const float*)d_in[4];
    const float* b_q          = (const float*)d_in[5];
    const float* w_kv         = (const float*)d_in[6];
    const float* b_kv         = (const float*)d_in[7];
    const float* w_qp         = (const float*)d_in[8];
    const float* b_qp         = (const float*)d_in[9];
    const float* w_kvp        = (const float*)d_in[10];
    const float* b_kvp        = (const float*)d_in[11];
    const float* head_weights = (const float*)d_in[12];
    const float* w_out        = (const float*)d_in[13];
    const float* b_out        = (const float*)d_in[14];
    float* out = (float*)d_out;
    float* ws  = (float*)d_ws;

    float* PROJ = ws + OFF_PROJ;
    float* KC   = ws + OFF_KC;
    float* O    = ws + OFF_O;
    float* OP   = ws + OFF_OP;
    float* CAT  = ws + OFF_CAT;   // aliases PROJ (dead after attn)

    proj_gemm<<<24 * 18, 256, 0, stream>>>(s, w_q, w_kv, w_qp, w_kvp, PROJ);
    pack_kernel<<<B_ * N_, 256, 0, stream>>>(PROJ, rot, trans, b_q, b_kv, b_qp, b_kvp,
                                             head_weights, KC);
    attn_kernel<<<B_ * H_ * (N_ / TI), 256, 0, stream>>>(PROJ, KC, pair_mask, O, OP);
    cat_kernel<<<B_ * N_, 128, 0, stream>>>(O, OP, rot, trans, CAT);
    out_gemm<<<24 * 6, 256, 0, stream>>>(CAT, w_out, b_out, out);
}

// Round 4
// 121.807 us; speedup vs baseline: 4.6949x; 1.4597x over previous
//
#include <hip/hip_runtime.h>
#include <hip/hip_bf16.h>
#include <math.h>

typedef __attribute__((ext_vector_type(4)))  short short4v;
typedef __attribute__((ext_vector_type(8)))  short short8;
typedef __attribute__((ext_vector_type(16))) float f32x16;

#define B_   2
#define N_   768
#define CN_  384
#define H_   12
#define INF_ 100000.0f
#define EPS_ 1e-7f

// ---------------- workspace layout (f32-slot offsets) ----------------
// PROJ f32 [1536][1152] (raw GEMM out; dead after pack2) -- arena reused by:
//   MB  bf16 [2][24][24][64][16]  at slot 0       (589824 slots)
//   Og  bf16 [1536][192]          at slot 589824  (147456 slots)
//   OPg bf16 [1536][288]          at slot 737280  (221184 slots)
//   CAT bf16 [1536][576]          at slot 958464  (442368 slots)
// Qf bf16 [24][768][32]  at 1769472
// Kf bf16 [24][768][32]  at 2064384
// Vt bf16 [24][64][768]  at 2359296   (rows 40..63 zero pad)
#define OFF_PROJ 0
#define OFF_MB   0
#define OFF_O    589824
#define OFF_OP   737280
#define OFF_CAT  958464
#define OFF_QF   1769472
#define OFF_KF   2064384
#define OFF_VT   2359296

__device__ inline float b2f(unsigned short u) {
    union { unsigned int i; float f; } x; x.i = ((unsigned int)u) << 16; return x.f;
}
__device__ inline unsigned short f2b(float f) {
    __hip_bfloat16 h = __float2bfloat16(f);
    return *reinterpret_cast<unsigned short*>(&h);
}

// ============================================================
// projection GEMM: proj[1536][1152] = S[1536][384] @ Wcat^T   (fp32)
// ============================================================
__global__ __launch_bounds__(256) void proj_gemm(
    const float* __restrict__ s,
    const float* __restrict__ w_q,  const float* __restrict__ w_kv,
    const float* __restrict__ w_qp, const float* __restrict__ w_kvp,
    float* __restrict__ proj)
{
    __shared__ float As[32][68];
    __shared__ float Bs[32][68];
    const int t = threadIdx.x;
    const int tile_n = blockIdx.x % 18;
    const int tile_m = blockIdx.x / 18;
    const int m0 = tile_m * 64, n0 = tile_n * 64;
    const int tx = t & 15, ty = t >> 4;

    const float* ap[8]; const float* bp[8];
    int ar[8], ac[8];
    #pragma unroll
    for (int e = 0; e < 8; ++e) {
        int idx = t + e * 256;
        int r = idx >> 5, c = idx & 31;
        ar[e] = r; ac[e] = c;
        ap[e] = s + (long)(m0 + r) * CN_ + c;
        int col = n0 + r;
        const float* wb;
        if (col < 192)      wb = w_q   + (long)col * CN_;
        else if (col < 576) wb = w_kv  + (long)(col - 192) * CN_;
        else if (col < 720) wb = w_qp  + (long)(col - 576) * CN_;
        else                wb = w_kvp + (long)(col - 720) * CN_;
        bp[e] = wb + c;
    }
    float acc[4][4] = {};
    for (int kt = 0; kt < CN_ / 32; ++kt) {
        const int k0 = kt * 32;
        __syncthreads();
        #pragma unroll
        for (int e = 0; e < 8; ++e) {
            As[ac[e]][ar[e]] = ap[e][k0];
            Bs[ac[e]][ar[e]] = bp[e][k0];
        }
        __syncthreads();
        #pragma unroll
        for (int kk = 0; kk < 32; ++kk) {
            float4 a4 = *(const float4*)&As[kk][ty * 4];
            float4 b4 = *(const float4*)&Bs[kk][tx * 4];
            float a[4] = {a4.x, a4.y, a4.z, a4.w};
            float b[4] = {b4.x, b4.y, b4.z, b4.w};
            #pragma unroll
            for (int i = 0; i < 4; ++i)
                #pragma unroll
                for (int j = 0; j < 4; ++j)
                    acc[i][j] += a[i] * b[j];
        }
    }
    #pragma unroll
    for (int i = 0; i < 4; ++i) {
        float4 st = {acc[i][0], acc[i][1], acc[i][2], acc[i][3]};
        *(float4*)(proj + (long)(m0 + ty * 4 + i) * 1152 + n0 + tx * 4) = st;
    }
}

// ============================================================
// pack2: bias + rotate/translate + scales -> bf16 frag-ready buffers
// Qf slots: [0:16) q/sqrt48, [16:28) hw*qp, 28=1, 29=1, 30,31=0
// Kf slots: [0:16) k, [16:28) kp, 28=kc_hi, 29=kc_lo, 30,31=0
// Vt[bh][d][n]: d 0..15 = v, 16..39 = vp, 40..63 = 0
// ============================================================
__global__ __launch_bounds__(256) void pack2_kernel(
    const float* __restrict__ proj,
    const float* __restrict__ rot, const float* __restrict__ trans,
    const float* __restrict__ b_q,  const float* __restrict__ b_kv,
    const float* __restrict__ b_qp, const float* __restrict__ b_kvp,
    const float* __restrict__ head_weights,
    unsigned short* __restrict__ Qf, unsigned short* __restrict__ Kf,
    unsigned short* __restrict__ Vt)
{
    __shared__ float raw[1152];
    __shared__ float pk[1152];
    __shared__ float rt[12];
    __shared__ float hws[12];
    __shared__ float kcs[12];
    const int bn = blockIdx.x;
    const int t  = threadIdx.x;
    const float* rowg = proj + (long)bn * 1152;
    for (int d = t; d < 1152; d += 256) {
        float bias = (d < 192) ? b_q[d] : (d < 576) ? b_kv[d - 192]
                   : (d < 720) ? b_qp[d - 576] : b_kvp[d - 720];
        raw[d] = rowg[d] + bias;
    }
    if (t < 9) rt[t]     = rot[bn * 9 + t];
    if (t < 3) rt[9 + t] = trans[bn * 3 + t];
    if (t < 12) {
        float v  = head_weights[t];
        float sp = (v > 20.f) ? v : log1pf(expf(v));
        hws[t] = sp * 0.13608276348795434f;  // softplus * sqrt(1/54)
    }
    __syncthreads();
    // per-head layout: h*96 + [0:16)q [16:28)qp*hw [28:44)k [44:56)kp [56:72)v [72:96)vp
    for (int slot = t; slot < 1152; slot += 256) {
        int hh = slot / 96, o = slot - hh * 96;
        float val;
        if (o < 16) {
            val = raw[hh * 16 + o] * 0.144337567297406f;  // 1/sqrt(48)
        } else if (o < 28) {
            int c = o - 16, p = c / 3, x = c - p * 3;
            float r0 = raw[576 +      hh * 4 + p];
            float r1 = raw[576 + 48 + hh * 4 + p];
            float r2 = raw[576 + 96 + hh * 4 + p];
            val = (rt[x*3]*r0 + rt[x*3+1]*r1 + rt[x*3+2]*r2 + rt[9+x]) * hws[hh];
        } else if (o < 44) {
            val = raw[192 + hh * 32 + (o - 28)];
        } else if (o < 56) {
            int c = o - 44, p = c / 3, x = c - p * 3;
            float r0 = raw[720 +       hh * 12 + p];
            float r1 = raw[720 + 144 + hh * 12 + p];
            float r2 = raw[720 + 288 + hh * 12 + p];
            val = rt[x*3]*r0 + rt[x*3+1]*r1 + rt[x*3+2]*r2 + rt[9+x];
        } else if (o < 72) {
            val = raw[192 + hh * 32 + 16 + (o - 56)];
        } else {
            int c = o - 72, p = c / 3, x = c - p * 3;
            float r0 = raw[720 +       hh * 12 + 4 + p];
            float r1 = raw[720 + 144 + hh * 12 + 4 + p];
            float r2 = raw[720 + 288 + hh * 12 + 4 + p];
            val = rt[x*3]*r0 + rt[x*3+1]*r1 + rt[x*3+2]*r2 + rt[9+x];
        }
        pk[slot] = val;
    }
    __syncthreads();
    if (t < 12) {
        float s2 = 0.f;
        #pragma unroll
        for (int e = 0; e < 12; ++e) { float v = pk[t * 96 + 44 + e]; s2 += v * v; }
        kcs[t] = -0.5f * hws[t] * s2;
    }
    __syncthreads();
    const int b = bn / N_, n = bn % N_;
    for (int d = t; d < 384; d += 256) {
        int hh = d >> 5, slot = d & 31;
        long base = ((long)(b * H_ + hh) * N_ + n) * 32 + slot;
        float qv, kv;
        if (slot < 28)      qv = pk[hh * 96 + slot];
        else if (slot < 30) qv = 1.f;
        else                qv = 0.f;
        if (slot < 16)      kv = pk[hh * 96 + 28 + slot];
        else if (slot < 28) kv = pk[hh * 96 + 44 + (slot - 16)];
        else if (slot == 28) kv = b2f(f2b(kcs[hh]));
        else if (slot == 29) kv = kcs[hh] - b2f(f2b(kcs[hh]));
        else                kv = 0.f;
        Qf[base] = f2b(qv);
        Kf[base] = f2b(kv);
    }
    for (int d = t; d < 480; d += 256) {
        int hh = d / 40, dd = d - hh * 40;
        Vt[((long)(b * H_ + hh) * 64 + dd) * N_ + n] = f2b(pk[hh * 96 + 56 + dd]);
    }
}

// ============================================================
// mask bias -> fragment-order bf16 buffer MB[b][it][jt][64][16]
// entry (l, reg) = INF*(mask[b][i0+(l&31)][j0+(reg&3)+8*(reg>>2)+4*(l>>5)] - 1)
// ============================================================
__global__ __launch_bounds__(256) void mb_pack(
    const float* __restrict__ mask, unsigned short* __restrict__ MB)
{
    const int tile = blockIdx.x;          // b*576 + it*24 + jt
    const int jt = tile % 24;
    const int it = (tile / 24) % 24;
    const int b  = tile / 576;
    const int t  = threadIdx.x;
    const int i0 = it * 32, j0 = jt * 32;
    unsigned short* out = MB + (long)tile * 1024;
    #pragma unroll
    for (int q = 0; q < 4; ++q) {
        int e = t * 4 + q;
        int l = e >> 4, reg = e & 15;
        int i = i0 + (l & 31);
        int j = j0 + (reg & 3) + 8 * (reg >> 2) + 4 * (l >> 5);
        float v = INF_ * (mask[((long)b * N_ + i) * N_ + j] - 1.f);
        out[e] = f2b(v);
    }
}

// ============================================================
// MFMA flash attention. Grid (b*12+h)*24+it, 512 threads = 8 waves.
// Wave w sweeps j in [w*96, w*96+96). No LDS in main loop; merge at end.
// k-slot<->j map for PV B operand chosen so each lane's own cvt_pk words ARE
// the fragment: k-slot hf*8+e  ->  j = hf*4 + (e<4 ? e : 4+e) pattern, i.e.
// j = hf*4 + {0,1,2,3,8,9,10,11}[e]  (chunk2: +16). V^T A-frags load at the
// matching offsets (two 8B loads per register operand).
// ============================================================
__global__ __launch_bounds__(512) void attn2_kernel(
    const unsigned short* __restrict__ Qf, const unsigned short* __restrict__ Kf,
    const unsigned short* __restrict__ Vt, const unsigned short* __restrict__ MB,
    unsigned short* __restrict__ Og, unsigned short* __restrict__ OPg)
{
    __shared__ float red[8][64][22];
    const int blk = blockIdx.x;
    const int it = blk % 24;
    const int bh = blk / 24;
    const int hh = bh % 12;
    const int b  = bh / 12;
    const int t  = threadIdx.x;
    const int w  = t >> 6;
    const int l  = t & 63;
    const int li = l & 31;
    const int hf = l >> 5;
    const int i0 = it * 32;

    const unsigned short* qbase = Qf + ((long)bh * N_ + i0 + li) * 32 + hf * 8;
    short8 q0 = *(const short8*)(qbase);
    short8 q1 = *(const short8*)(qbase + 16);

    f32x16 acc0 = {};
    f32x16 acc1 = {};
    float m = -1e30f, lsum = 0.f;
    const unsigned short* vtb = Vt + (long)bh * 64 * N_;
    const unsigned short* mbb = MB + ((long)(b * 24 + it)) * 24 * 1024;

    for (int jt = w * 3; jt < w * 3 + 3; ++jt) {
        const int j0 = jt * 32;
        // C-init from mask-bias fragments
        const unsigned short* mbp = mbb + (long)jt * 1024 + l * 16;
        short8 mb0 = *(const short8*)(mbp);
        short8 mb1 = *(const short8*)(mbp + 8);
        f32x16 S;
        #pragma unroll
        for (int r = 0; r < 8; ++r) S[r]     = b2f((unsigned short)mb0[r]);
        #pragma unroll
        for (int r = 0; r < 8; ++r) S[8 + r] = b2f((unsigned short)mb1[r]);
        // K fragments (lane: j=li, k chunk hf*8; chunks k0..15 / k16..31)
        const unsigned short* kp = Kf + ((long)bh * N_ + j0 + li) * 32 + hf * 8;
        short8 k0 = *(const short8*)(kp);
        short8 k1 = *(const short8*)(kp + 16);
        // S^T[j][i] = sum_k K[j][k] Q[i][k]  (lane holds col i=li, 16 j rows)
        S = __builtin_amdgcn_mfma_f32_32x32x16_bf16(k0, q0, S, 0, 0, 0);
        S = __builtin_amdgcn_mfma_f32_32x32x16_bf16(k1, q1, S, 0, 0, 0);
        // online softmax for row i=li; halves exchange via permlane32_swap.
        // Use BOTH returned elements -> ordering-agnostic reduce.
        float mloc = S[0];
        #pragma unroll
        for (int r = 1; r < 16; ++r) mloc = fmaxf(mloc, S[r]);
        {
            auto mm = __builtin_amdgcn_permlane32_swap(
                __float_as_int(mloc), __float_as_int(mloc), false, false);
            mloc = fmaxf(__int_as_float(mm[0]), __int_as_float(mm[1]));
        }
        float newm = fmaxf(m, mloc);
        float scale = __expf(m - newm);
        float ps = 0.f;
        f32x16 p;
        #pragma unroll
        for (int r = 0; r < 16; ++r) { p[r] = __expf(S[r] - newm); ps += p[r]; }
        {
            auto ss = __builtin_amdgcn_permlane32_swap(
                __float_as_int(ps), __float_as_int(ps), false, false);
            ps = __int_as_float(ss[0]) + __int_as_float(ss[1]);
        }
        lsum = lsum * scale + ps;
        m = newm;
        #pragma unroll
        for (int r = 0; r < 16; ++r) acc0[r] *= scale;
        #pragma unroll
        for (int r = 0; r < 4; ++r)  acc1[r] *= scale;
        // pack p -> PV B-fragments: lane's own cvt_pk words, in order.
        // p[r] holds j_r = (r&3)+8*(r>>2)+4*hf; c[r]={p[2r],p[2r+1]} ->
        // chunk1 frag dwords {c0,c1,c2,c3} = j {hf*4+0..3, 8+hf*4+0..3}
        // chunk2 frag dwords {c4,c5,c6,c7} = j {16+hf*4+0..3, 24+hf*4+0..3}
        int c[8];
        #pragma unroll
        for (int r = 0; r < 8; ++r) {
            asm("v_cvt_pk_bf16_f32 %0, %1, %2" : "=v"(c[r]) : "v"(p[2*r]), "v"(p[2*r+1]));
        }
        union { int w4[4]; short8 v; } bf0, bf1;
        bf0.w4[0] = c[0]; bf0.w4[1] = c[1]; bf0.w4[2] = c[2]; bf0.w4[3] = c[3];
        bf1.w4[0] = c[4]; bf1.w4[1] = c[5]; bf1.w4[2] = c[6]; bf1.w4[3] = c[7];
        // V^T A-frags at the matching interleaved j offsets (two 8B loads each)
        union { short4v h[2]; short8 v; } v00, v01, v10, v11;
        const unsigned short* vr0 = vtb + (long)li * N_        + j0 + hf * 4;
        const unsigned short* vr1 = vtb + (long)(32 + li) * N_ + j0 + hf * 4;
        v00.h[0] = *(const short4v*)(vr0);       v00.h[1] = *(const short4v*)(vr0 + 8);
        v01.h[0] = *(const short4v*)(vr1);       v01.h[1] = *(const short4v*)(vr1 + 8);
        v10.h[0] = *(const short4v*)(vr0 + 16);  v10.h[1] = *(const short4v*)(vr0 + 24);
        v11.h[0] = *(const short4v*)(vr1 + 16);  v11.h[1] = *(const short4v*)(vr1 + 24);
        acc0 = __builtin_amdgcn_mfma_f32_32x32x16_bf16(v00.v, bf0.v, acc0, 0, 0, 0);
        acc1 = __builtin_amdgcn_mfma_f32_32x32x16_bf16(v01.v, bf0.v, acc1, 0, 0, 0);
        acc0 = __builtin_amdgcn_mfma_f32_32x32x16_bf16(v10.v, bf1.v, acc0, 0, 0, 0);
        acc1 = __builtin_amdgcn_mfma_f32_32x32x16_bf16(v11.v, bf1.v, acc1, 0, 0, 0);
    }
    // per-wave partials -> LDS
    float* rd = &red[w][l][0];
    rd[0] = m; rd[1] = lsum;
    #pragma unroll
    for (int r = 0; r < 16; ++r) rd[2 + r]  = acc0[r];
    #pragma unroll
    for (int r = 0; r < 4; ++r)  rd[18 + r] = acc1[r];
    __syncthreads();
    // merge 8 chunks: thread group g=t>>6 handles regs {g, g+8, g+16} of slot l2
    {
        const int l2 = t & 63, g = t >> 6;
        const int li2 = l2 & 31, hf2 = l2 >> 5;
        float ms = -1e30f;
        #pragma unroll
        for (int ww = 0; ww < 8; ++ww) ms = fmaxf(ms, red[ww][l2][0]);
        float wt[8]; float lf = 0.f;
        #pragma unroll
        for (int ww = 0; ww < 8; ++ww) {
            wt[ww] = __expf(red[ww][l2][0] - ms);
            lf += wt[ww] * red[ww][l2][1];
        }
        float inv = 1.f / lf;
        const int n = i0 + li2;
        #pragma unroll
        for (int rr = 0; rr < 3; ++rr) {
            int r = g + rr * 8;
            if (r < 20) {
                float v = 0.f;
                #pragma unroll
                for (int ww = 0; ww < 8; ++ww) v += wt[ww] * red[ww][l2][2 + r];
                v *= inv;
                int d = (r < 16) ? ((r & 3) + 8 * (r >> 2) + 4 * hf2)
                                 : (32 + (r - 16) + 4 * hf2);
                unsigned short ov = f2b(v);
                if (d < 16) Og [((long)(b * N_ + n)) * 192 + hh * 16 + d] = ov;
                else        OPg[((long)(b * N_ + n)) * 288 + hh * 24 + (d - 16)] = ov;
            }
        }
    }
}

// ============================================================
// cat build: inverse rotation + norms -> cat[1536][576] bf16
// ============================================================
__global__ __launch_bounds__(128) void cat_kernel(
    const unsigned short* __restrict__ Og, const unsigned short* __restrict__ OPg,
    const float* __restrict__ rot, const float* __restrict__ trans,
    unsigned short* __restrict__ catg)
{
    __shared__ float cat[576];
    __shared__ float rt[12];
    const int bn = blockIdx.x;
    const int t  = threadIdx.x;
    if (t < 9) rt[t]     = rot[bn * 9 + t];
    if (t < 3) rt[9 + t] = trans[bn * 3 + t];
    for (int d = t; d < 192; d += 128) cat[d] = b2f(Og[(long)bn * 192 + d]);
    __syncthreads();
    if (t < 96) {
        float g0 = b2f(OPg[(long)bn * 288 + t * 3 + 0]) - rt[9];
        float g1 = b2f(OPg[(long)bn * 288 + t * 3 + 1]) - rt[10];
        float g2 = b2f(OPg[(long)bn * 288 + t * 3 + 2]) - rt[11];
        float l0 = rt[0]*g0 + rt[3]*g1 + rt[6]*g2;
        float l1 = rt[1]*g0 + rt[4]*g1 + rt[7]*g2;
        float l2 = rt[2]*g0 + rt[5]*g1 + rt[8]*g2;
        cat[192 + t] = l0;
        cat[288 + t] = l1;
        cat[384 + t] = l2;
        cat[480 + t] = sqrtf(l0*l0 + l1*l1 + l2*l2 + EPS_);
    }
    __syncthreads();
    for (int d = t; d < 576; d += 128) catg[(long)bn * 576 + d] = f2b(cat[d]);
}

// ============================================================
// output GEMM: out[1536][384] = cat(bf16)[1536][576] @ w_out^T + b_out
// ============================================================
__global__ __launch_bounds__(256) void out_gemm(
    const unsigned short* __restrict__ catg, const float* __restrict__ w_out,
    const float* __restrict__ b_out, float* __restrict__ out)
{
    __shared__ float As[32][68];
    __shared__ float Bs[32][68];
    const int t = threadIdx.x;
    const int tile_n = blockIdx.x % 6;
    const int tile_m = blockIdx.x / 6;
    const int m0 = tile_m * 64, n0 = tile_n * 64;
    const int tx = t & 15, ty = t >> 4;

    const float* bp[8]; int br[8], bc[8];
    #pragma unroll
    for (int e = 0; e < 8; ++e) {
        int idx = t + e * 256;
        int r = idx >> 5, c = idx & 31;
        br[e] = r; bc[e] = c;
        bp[e] = w_out + (long)(n0 + r) * 576 + c;
    }
    const int rr = t >> 2, cc = (t & 3) * 8;
    float acc[4][4] = {};
    for (int kt = 0; kt < 18; ++kt) {
        const int k0 = kt * 32;
        __syncthreads();
        {
            short8 a8 = *(const short8*)(catg + (long)(m0 + rr) * 576 + k0 + cc);
            #pragma unroll
            for (int e = 0; e < 8; ++e) As[cc + e][rr] = b2f((unsigned short)a8[e]);
        }
        #pragma unroll
        for (int e = 0; e < 8; ++e) Bs[bc[e]][br[e]] = bp[e][k0];
        __syncthreads();
        #pragma unroll
        for (int kk = 0; kk < 32; ++kk) {
            float4 a4 = *(const float4*)&As[kk][ty * 4];
            float4 b4 = *(const float4*)&Bs[kk][tx * 4];
            float a[4] = {a4.x, a4.y, a4.z, a4.w};
            float b[4] = {b4.x, b4.y, b4.z, b4.w};
            #pragma unroll
            for (int i = 0; i < 4; ++i)
                #pragma unroll
                for (int j = 0; j < 4; ++j)
                    acc[i][j] += a[i] * b[j];
        }
    }
    float4 bb = *(const float4*)(b_out + n0 + tx * 4);
    #pragma unroll
    for (int i = 0; i < 4; ++i) {
        float4 st = {acc[i][0] + bb.x, acc[i][1] + bb.y,
                     acc[i][2] + bb.z, acc[i][3] + bb.w};
        *(float4*)(out + (long)(m0 + ty * 4 + i) * 384 + n0 + tx * 4) = st;
    }
}

// ============================================================
extern "C" void kernel_launch(void* const* d_in, const int* in_sizes, int n_in,
                              void* d_out, int out_size, void* d_ws, size_t ws_size,
                              hipStream_t stream) {
    const float* s            = (const float*)d_in[0];
    const float* rot          = (const float*)d_in[1];
    const float* trans        = (const float*)d_in[2];
    const float* pair_mask    = (const float*)d_in[3];
    const float* w_q          = (const float*)d_in[4];
    const float* b_q          = (const float*)d_in[5];
    const float* w_kv         = (const float*)d_in[6];
    const float* b_kv         = (const float*)d_in[7];
    const float* w_qp         = (const float*)d_in[8];
    const float* b_qp         = (const float*)d_in[9];
    const float* w_kvp        = (const float*)d_in[10];
    const float* b_kvp        = (const float*)d_in[11];
    const float* head_weights = (const float*)d_in[12];
    const float* w_out        = (const float*)d_in[13];
    const float* b_out        = (const float*)d_in[14];
    float* out = (float*)d_out;
    float* ws  = (float*)d_ws;

    float*          PROJ = ws + OFF_PROJ;
    unsigned short* MBp  = (unsigned short*)(ws + OFF_MB);
    unsigned short* Og   = (unsigned short*)(ws + OFF_O);
    unsigned short* OPg  = (unsigned short*)(ws + OFF_OP);
    unsigned short* CAT  = (unsigned short*)(ws + OFF_CAT);
    unsigned short* Qf   = (unsigned short*)(ws + OFF_QF);
    unsigned short* Kf   = (unsigned short*)(ws + OFF_KF);
    unsigned short* Vt   = (unsigned short*)(ws + OFF_VT);

    // zero Vt (pad rows 40..63 must be 0 for the PV d-tile-1 MFMA)
    (void)hipMemsetAsync(ws + OFF_VT, 0, 589824 * sizeof(float), stream);
    proj_gemm<<<24 * 18, 256, 0, stream>>>(s, w_q, w_kv, w_qp, w_kvp, PROJ);
    pack2_kernel<<<B_ * N_, 256, 0, stream>>>(PROJ, rot, trans, b_q, b_kv, b_qp, b_kvp,
                                              head_weights, Qf, Kf, Vt);
    mb_pack<<<B_ * 24 * 24, 256, 0, stream>>>(pair_mask, MBp);   // after pack2: aliases PROJ
    attn2_kernel<<<B_ * H_ * 24, 512, 0, stream>>>(Qf, Kf, Vt, MBp, Og, OPg);
    cat_kernel<<<B_ * N_, 128, 0, stream>>>(Og, OPg, rot, trans, CAT);
    out_gemm<<<24 * 6, 256, 0, stream>>>(CAT, w_out, b_out, out);
}

// Round 5
// 86.307 us; speedup vs baseline: 6.6260x; 1.4113x over previous
//
#include <hip/hip_runtime.h>
#include <hip/hip_bf16.h>
#include <math.h>

typedef __attribute__((ext_vector_type(4)))  short short4v;
typedef __attribute__((ext_vector_type(8)))  short short8;
typedef __attribute__((ext_vector_type(16))) float f32x16;

#define B_   2
#define N_   768
#define CN_  384
#define H_   12
#define INF_ 100000.0f
#define EPS_ 1e-7f

// ---------------- workspace layout (f32-slot offsets) ----------------
// PROJ f32 [1536][1152] (bias-added GEMM out; dead after pack2) -- arena reused by:
//   MB  bf16 [2][24][24][64][16]  at slot 0       (589824 slots)
//   Og  bf16 [1536][192]          at slot 589824  (147456 slots)
//   OPg bf16 [1536][288]          at slot 737280  (221184 slots)
//   CAT bf16 [1536][576]          at slot 958464  (442368 slots)
// Qf bf16 [24][768][32]  at 1769472
// Kf bf16 [24][768][32]  at 2064384
// Vt bf16 [24][64][768]  at 2359296   (rows 40..63 zero pad)
#define OFF_PROJ 0
#define OFF_MB   0
#define OFF_O    589824
#define OFF_OP   737280
#define OFF_CAT  958464
#define OFF_QF   1769472
#define OFF_KF   2064384
#define OFF_VT   2359296

__device__ inline float b2f(unsigned short u) {
    union { unsigned int i; float f; } x; x.i = ((unsigned int)u) << 16; return x.f;
}
__device__ inline unsigned short f2b(float f) {
    __hip_bfloat16 h = __float2bfloat16(f);
    return *reinterpret_cast<unsigned short*>(&h);
}
__device__ inline short8 cvt8(float4 f0, float4 f1) {
    short8 r;
    r[0] = (short)f2b(f0.x); r[1] = (short)f2b(f0.y);
    r[2] = (short)f2b(f0.z); r[3] = (short)f2b(f0.w);
    r[4] = (short)f2b(f1.x); r[5] = (short)f2b(f1.y);
    r[6] = (short)f2b(f1.z); r[7] = (short)f2b(f1.w);
    return r;
}

// ============================================================
// projection GEMM (MFMA): proj[1536][1152] = S @ Wcat^T + bias
// one wave per 32x32 tile; A=s rows, B=weight rows, bf16 cvt in-flight.
// D: col = c0 + (lane&31), row = r0 + (reg&3)+8*(reg>>2)+4*(lane>>5)
// ============================================================
__global__ __launch_bounds__(64) void proj_mfma(
    const float* __restrict__ s,
    const float* __restrict__ w_q,  const float* __restrict__ w_kv,
    const float* __restrict__ w_qp, const float* __restrict__ w_kvp,
    const float* __restrict__ b_q,  const float* __restrict__ b_kv,
    const float* __restrict__ b_qp, const float* __restrict__ b_kvp,
    float* __restrict__ proj)
{
    const int tile = blockIdx.x;          // 48 * 36
    const int tn = tile % 36, tm = tile / 36;
    const int r0 = tm * 32, c0 = tn * 32;
    const int l  = threadIdx.x;
    const int li = l & 31, hf = l >> 5;

    const float* ap = s + (long)(r0 + li) * CN_ + hf * 8;
    const int col = c0 + li;
    const float* wb; float bias;
    if (col < 192)      { wb = w_q   + (long)col * CN_;        bias = b_q[col]; }
    else if (col < 576) { wb = w_kv  + (long)(col - 192) * CN_; bias = b_kv[col - 192]; }
    else if (col < 720) { wb = w_qp  + (long)(col - 576) * CN_; bias = b_qp[col - 576]; }
    else                { wb = w_kvp + (long)(col - 720) * CN_; bias = b_kvp[col - 720]; }
    wb += hf * 8;

    f32x16 acc = {};
    for (int k = 0; k < CN_; k += 32) {   // 2 MFMA per iter for ILP
        float4 a00 = *(const float4*)(ap + k);
        float4 a01 = *(const float4*)(ap + k + 4);
        float4 b00 = *(const float4*)(wb + k);
        float4 b01 = *(const float4*)(wb + k + 4);
        float4 a10 = *(const float4*)(ap + k + 16);
        float4 a11 = *(const float4*)(ap + k + 20);
        float4 b10 = *(const float4*)(wb + k + 16);
        float4 b11 = *(const float4*)(wb + k + 20);
        acc = __builtin_amdgcn_mfma_f32_32x32x16_bf16(cvt8(a00, a01), cvt8(b00, b01), acc, 0, 0, 0);
        acc = __builtin_amdgcn_mfma_f32_32x32x16_bf16(cvt8(a10, a11), cvt8(b10, b11), acc, 0, 0, 0);
    }
    #pragma unroll
    for (int r = 0; r < 16; ++r) {
        int row = r0 + (r & 3) + 8 * (r >> 2) + 4 * hf;
        proj[(long)row * 1152 + col] = acc[r] + bias;
    }
}

// ============================================================
// pack2: rotate/translate + scales -> bf16 frag-ready buffers (bias already in proj)
// Qf slots: [0:16) q/sqrt48, [16:28) hw*qp, 28=1, 29=1, 30,31=0
// Kf slots: [0:16) k, [16:28) kp, 28=kc_hi, 29=kc_lo, 30,31=0
// Vt[bh][d][n]: d 0..15 = v, 16..39 = vp, 40..63 = 0
// ============================================================
__global__ __launch_bounds__(256) void pack2_kernel(
    const float* __restrict__ proj,
    const float* __restrict__ rot, const float* __restrict__ trans,
    const float* __restrict__ head_weights,
    unsigned short* __restrict__ Qf, unsigned short* __restrict__ Kf,
    unsigned short* __restrict__ Vt)
{
    __shared__ float raw[1152];
    __shared__ float pk[1152];
    __shared__ float rt[12];
    __shared__ float hws[12];
    __shared__ float kcs[12];
    const int bn = blockIdx.x;
    const int t  = threadIdx.x;
    const float* rowg = proj + (long)bn * 1152;
    for (int d = t; d < 1152; d += 256) raw[d] = rowg[d];
    if (t < 9) rt[t]     = rot[bn * 9 + t];
    if (t < 3) rt[9 + t] = trans[bn * 3 + t];
    if (t < 12) {
        float v  = head_weights[t];
        float sp = (v > 20.f) ? v : log1pf(expf(v));
        hws[t] = sp * 0.13608276348795434f;  // softplus * sqrt(1/54)
    }
    __syncthreads();
    // per-head layout: h*96 + [0:16)q [16:28)qp*hw [28:44)k [44:56)kp [56:72)v [72:96)vp
    for (int slot = t; slot < 1152; slot += 256) {
        int hh = slot / 96, o = slot - hh * 96;
        float val;
        if (o < 16) {
            val = raw[hh * 16 + o] * 0.144337567297406f;  // 1/sqrt(48)
        } else if (o < 28) {
            int c = o - 16, p = c / 3, x = c - p * 3;
            float r0 = raw[576 +      hh * 4 + p];
            float r1 = raw[576 + 48 + hh * 4 + p];
            float r2 = raw[576 + 96 + hh * 4 + p];
            val = (rt[x*3]*r0 + rt[x*3+1]*r1 + rt[x*3+2]*r2 + rt[9+x]) * hws[hh];
        } else if (o < 44) {
            val = raw[192 + hh * 32 + (o - 28)];
        } else if (o < 56) {
            int c = o - 44, p = c / 3, x = c - p * 3;
            float r0 = raw[720 +       hh * 12 + p];
            float r1 = raw[720 + 144 + hh * 12 + p];
            float r2 = raw[720 + 288 + hh * 12 + p];
            val = rt[x*3]*r0 + rt[x*3+1]*r1 + rt[x*3+2]*r2 + rt[9+x];
        } else if (o < 72) {
            val = raw[192 + hh * 32 + 16 + (o - 56)];
        } else {
            int c = o - 72, p = c / 3, x = c - p * 3;
            float r0 = raw[720 +       hh * 12 + 4 + p];
            float r1 = raw[720 + 144 + hh * 12 + 4 + p];
            float r2 = raw[720 + 288 + hh * 12 + 4 + p];
            val = rt[x*3]*r0 + rt[x*3+1]*r1 + rt[x*3+2]*r2 + rt[9+x];
        }
        pk[slot] = val;
    }
    __syncthreads();
    if (t < 12) {
        float s2 = 0.f;
        #pragma unroll
        for (int e = 0; e < 12; ++e) { float v = pk[t * 96 + 44 + e]; s2 += v * v; }
        kcs[t] = -0.5f * hws[t] * s2;
    }
    __syncthreads();
    const int b = bn / N_, n = bn % N_;
    for (int d = t; d < 384; d += 256) {
        int hh = d >> 5, slot = d & 31;
        long base = ((long)(b * H_ + hh) * N_ + n) * 32 + slot;
        float qv, kv;
        if (slot < 28)      qv = pk[hh * 96 + slot];
        else if (slot < 30) qv = 1.f;
        else                qv = 0.f;
        if (slot < 16)      kv = pk[hh * 96 + 28 + slot];
        else if (slot < 28) kv = pk[hh * 96 + 44 + (slot - 16)];
        else if (slot == 28) kv = b2f(f2b(kcs[hh]));
        else if (slot == 29) kv = kcs[hh] - b2f(f2b(kcs[hh]));
        else                kv = 0.f;
        Qf[base] = f2b(qv);
        Kf[base] = f2b(kv);
    }
    for (int d = t; d < 480; d += 256) {
        int hh = d / 40, dd = d - hh * 40;
        Vt[((long)(b * H_ + hh) * 64 + dd) * N_ + n] = f2b(pk[hh * 96 + 56 + dd]);
    }
}

// ============================================================
// mask bias -> fragment-order bf16 buffer MB[b][it][jt][64][16]
// entry (l, reg) = INF*(mask[b][i0+(l&31)][j0+(reg&3)+8*(reg>>2)+4*(l>>5)] - 1)
// ============================================================
__global__ __launch_bounds__(256) void mb_pack(
    const float* __restrict__ mask, unsigned short* __restrict__ MB)
{
    const int tile = blockIdx.x;          // b*576 + it*24 + jt
    const int jt = tile % 24;
    const int it = (tile / 24) % 24;
    const int b  = tile / 576;
    const int t  = threadIdx.x;
    const int i0 = it * 32, j0 = jt * 32;
    unsigned short* out = MB + (long)tile * 1024;
    #pragma unroll
    for (int q = 0; q < 4; ++q) {
        int e = t * 4 + q;
        int l = e >> 4, reg = e & 15;
        int i = i0 + (l & 31);
        int j = j0 + (reg & 3) + 8 * (reg >> 2) + 4 * (l >> 5);
        float v = INF_ * (mask[((long)b * N_ + i) * N_ + j] - 1.f);
        out[e] = f2b(v);
    }
}

// ============================================================
// MFMA flash attention. Grid (b*12+h)*24+it, 512 threads = 8 waves.
// Wave w sweeps j in [w*96, w*96+96). No LDS in main loop; merge at end.
// ============================================================
__global__ __launch_bounds__(512) void attn2_kernel(
    const unsigned short* __restrict__ Qf, const unsigned short* __restrict__ Kf,
    const unsigned short* __restrict__ Vt, const unsigned short* __restrict__ MB,
    unsigned short* __restrict__ Og, unsigned short* __restrict__ OPg)
{
    __shared__ float red[8][64][22];
    const int blk = blockIdx.x;
    const int it = blk % 24;
    const int bh = blk / 24;
    const int hh = bh % 12;
    const int b  = bh / 12;
    const int t  = threadIdx.x;
    const int w  = t >> 6;
    const int l  = t & 63;
    const int li = l & 31;
    const int hf = l >> 5;
    const int i0 = it * 32;

    const unsigned short* qbase = Qf + ((long)bh * N_ + i0 + li) * 32 + hf * 8;
    short8 q0 = *(const short8*)(qbase);
    short8 q1 = *(const short8*)(qbase + 16);

    f32x16 acc0 = {};
    f32x16 acc1 = {};
    float m = -1e30f, lsum = 0.f;
    const unsigned short* vtb = Vt + (long)bh * 64 * N_;
    const unsigned short* mbb = MB + ((long)(b * 24 + it)) * 24 * 1024;

    for (int jt = w * 3; jt < w * 3 + 3; ++jt) {
        const int j0 = jt * 32;
        // C-init from mask-bias fragments
        const unsigned short* mbp = mbb + (long)jt * 1024 + l * 16;
        short8 mb0 = *(const short8*)(mbp);
        short8 mb1 = *(const short8*)(mbp + 8);
        f32x16 S;
        #pragma unroll
        for (int r = 0; r < 8; ++r) S[r]     = b2f((unsigned short)mb0[r]);
        #pragma unroll
        for (int r = 0; r < 8; ++r) S[8 + r] = b2f((unsigned short)mb1[r]);
        // K fragments (lane: j=li, k chunk hf*8; chunks k0..15 / k16..31)
        const unsigned short* kp = Kf + ((long)bh * N_ + j0 + li) * 32 + hf * 8;
        short8 k0 = *(const short8*)(kp);
        short8 k1 = *(const short8*)(kp + 16);
        // S^T[j][i] = sum_k K[j][k] Q[i][k]  (lane holds col i=li, 16 j rows)
        S = __builtin_amdgcn_mfma_f32_32x32x16_bf16(k0, q0, S, 0, 0, 0);
        S = __builtin_amdgcn_mfma_f32_32x32x16_bf16(k1, q1, S, 0, 0, 0);
        // online softmax for row i=li; halves exchange via permlane32_swap.
        float mloc = S[0];
        #pragma unroll
        for (int r = 1; r < 16; ++r) mloc = fmaxf(mloc, S[r]);
        {
            auto mm = __builtin_amdgcn_permlane32_swap(
                __float_as_int(mloc), __float_as_int(mloc), false, false);
            mloc = fmaxf(__int_as_float(mm[0]), __int_as_float(mm[1]));
        }
        float newm = fmaxf(m, mloc);
        float scale = __expf(m - newm);
        float ps = 0.f;
        f32x16 p;
        #pragma unroll
        for (int r = 0; r < 16; ++r) { p[r] = __expf(S[r] - newm); ps += p[r]; }
        {
            auto ss = __builtin_amdgcn_permlane32_swap(
                __float_as_int(ps), __float_as_int(ps), false, false);
            ps = __int_as_float(ss[0]) + __int_as_float(ss[1]);
        }
        lsum = lsum * scale + ps;
        m = newm;
        #pragma unroll
        for (int r = 0; r < 16; ++r) acc0[r] *= scale;
        #pragma unroll
        for (int r = 0; r < 4; ++r)  acc1[r] *= scale;
        // pack p -> PV B-fragments: lane's own cvt_pk words, in order.
        int c[8];
        #pragma unroll
        for (int r = 0; r < 8; ++r) {
            asm("v_cvt_pk_bf16_f32 %0, %1, %2" : "=v"(c[r]) : "v"(p[2*r]), "v"(p[2*r+1]));
        }
        union { int w4[4]; short8 v; } bf0, bf1;
        bf0.w4[0] = c[0]; bf0.w4[1] = c[1]; bf0.w4[2] = c[2]; bf0.w4[3] = c[3];
        bf1.w4[0] = c[4]; bf1.w4[1] = c[5]; bf1.w4[2] = c[6]; bf1.w4[3] = c[7];
        // V^T A-frags at the matching interleaved j offsets (two 8B loads each)
        union { short4v h[2]; short8 v; } v00, v01, v10, v11;
        const unsigned short* vr0 = vtb + (long)li * N_        + j0 + hf * 4;
        const unsigned short* vr1 = vtb + (long)(32 + li) * N_ + j0 + hf * 4;
        v00.h[0] = *(const short4v*)(vr0);       v00.h[1] = *(const short4v*)(vr0 + 8);
        v01.h[0] = *(const short4v*)(vr1);       v01.h[1] = *(const short4v*)(vr1 + 8);
        v10.h[0] = *(const short4v*)(vr0 + 16);  v10.h[1] = *(const short4v*)(vr0 + 24);
        v11.h[0] = *(const short4v*)(vr1 + 16);  v11.h[1] = *(const short4v*)(vr1 + 24);
        acc0 = __builtin_amdgcn_mfma_f32_32x32x16_bf16(v00.v, bf0.v, acc0, 0, 0, 0);
        acc1 = __builtin_amdgcn_mfma_f32_32x32x16_bf16(v01.v, bf0.v, acc1, 0, 0, 0);
        acc0 = __builtin_amdgcn_mfma_f32_32x32x16_bf16(v10.v, bf1.v, acc0, 0, 0, 0);
        acc1 = __builtin_amdgcn_mfma_f32_32x32x16_bf16(v11.v, bf1.v, acc1, 0, 0, 0);
    }
    // per-wave partials -> LDS
    float* rd = &red[w][l][0];
    rd[0] = m; rd[1] = lsum;
    #pragma unroll
    for (int r = 0; r < 16; ++r) rd[2 + r]  = acc0[r];
    #pragma unroll
    for (int r = 0; r < 4; ++r)  rd[18 + r] = acc1[r];
    __syncthreads();
    // merge 8 chunks: thread group g=t>>6 handles regs {g, g+8, g+16} of slot l2
    {
        const int l2 = t & 63, g = t >> 6;
        const int li2 = l2 & 31, hf2 = l2 >> 5;
        float ms = -1e30f;
        #pragma unroll
        for (int ww = 0; ww < 8; ++ww) ms = fmaxf(ms, red[ww][l2][0]);
        float wt[8]; float lf = 0.f;
        #pragma unroll
        for (int ww = 0; ww < 8; ++ww) {
            wt[ww] = __expf(red[ww][l2][0] - ms);
            lf += wt[ww] * red[ww][l2][1];
        }
        float inv = 1.f / lf;
        const int n = i0 + li2;
        #pragma unroll
        for (int rr = 0; rr < 3; ++rr) {
            int r = g + rr * 8;
            if (r < 20) {
                float v = 0.f;
                #pragma unroll
                for (int ww = 0; ww < 8; ++ww) v += wt[ww] * red[ww][l2][2 + r];
                v *= inv;
                int d = (r < 16) ? ((r & 3) + 8 * (r >> 2) + 4 * hf2)
                                 : (32 + (r - 16) + 4 * hf2);
                unsigned short ov = f2b(v);
                if (d < 16) Og [((long)(b * N_ + n)) * 192 + hh * 16 + d] = ov;
                else        OPg[((long)(b * N_ + n)) * 288 + hh * 24 + (d - 16)] = ov;
            }
        }
    }
}

// ============================================================
// cat build: inverse rotation + norms -> cat[1536][576] bf16
// ============================================================
__global__ __launch_bounds__(128) void cat_kernel(
    const unsigned short* __restrict__ Og, const unsigned short* __restrict__ OPg,
    const float* __restrict__ rot, const float* __restrict__ trans,
    unsigned short* __restrict__ catg)
{
    __shared__ float cat[576];
    __shared__ float rt[12];
    const int bn = blockIdx.x;
    const int t  = threadIdx.x;
    if (t < 9) rt[t]     = rot[bn * 9 + t];
    if (t < 3) rt[9 + t] = trans[bn * 3 + t];
    for (int d = t; d < 192; d += 128) cat[d] = b2f(Og[(long)bn * 192 + d]);
    __syncthreads();
    if (t < 96) {
        float g0 = b2f(OPg[(long)bn * 288 + t * 3 + 0]) - rt[9];
        float g1 = b2f(OPg[(long)bn * 288 + t * 3 + 1]) - rt[10];
        float g2 = b2f(OPg[(long)bn * 288 + t * 3 + 2]) - rt[11];
        float l0 = rt[0]*g0 + rt[3]*g1 + rt[6]*g2;
        float l1 = rt[1]*g0 + rt[4]*g1 + rt[7]*g2;
        float l2 = rt[2]*g0 + rt[5]*g1 + rt[8]*g2;
        cat[192 + t] = l0;
        cat[288 + t] = l1;
        cat[384 + t] = l2;
        cat[480 + t] = sqrtf(l0*l0 + l1*l1 + l2*l2 + EPS_);
    }
    __syncthreads();
    for (int d = t; d < 576; d += 128) catg[(long)bn * 576 + d] = f2b(cat[d]);
}

// ============================================================
// output GEMM (MFMA): out[1536][384] = cat(bf16) @ w_out^T + b_out
// one wave per 32x32 tile; w_out converted bf16 in-flight.
// ============================================================
__global__ __launch_bounds__(64) void out_mfma(
    const unsigned short* __restrict__ catg,  // [1536][576] bf16
    const float* __restrict__ w_out,          // [384][576]
    const float* __restrict__ b_out,
    float* __restrict__ out)
{
    const int tile = blockIdx.x;          // 48 * 12
    const int tn = tile % 12, tm = tile / 12;
    const int r0 = tm * 32, c0 = tn * 32;
    const int l  = threadIdx.x;
    const int li = l & 31, hf = l >> 5;

    const unsigned short* ap = catg + (long)(r0 + li) * 576 + hf * 8;
    const float* wp = w_out + (long)(c0 + li) * 576 + hf * 8;

    f32x16 acc = {};
    for (int k = 0; k < 576; k += 32) {   // 2 MFMA per iter
        short8 a0 = *(const short8*)(ap + k);
        short8 a1 = *(const short8*)(ap + k + 16);
        float4 b00 = *(const float4*)(wp + k);
        float4 b01 = *(const float4*)(wp + k + 4);
        float4 b10 = *(const float4*)(wp + k + 16);
        float4 b11 = *(const float4*)(wp + k + 20);
        acc = __builtin_amdgcn_mfma_f32_32x32x16_bf16(a0, cvt8(b00, b01), acc, 0, 0, 0);
        acc = __builtin_amdgcn_mfma_f32_32x32x16_bf16(a1, cvt8(b10, b11), acc, 0, 0, 0);
    }
    float bias = b_out[c0 + li];
    #pragma unroll
    for (int r = 0; r < 16; ++r) {
        int row = r0 + (r & 3) + 8 * (r >> 2) + 4 * hf;
        out[(long)row * 384 + c0 + li] = acc[r] + bias;
    }
}

// ============================================================
extern "C" void kernel_launch(void* const* d_in, const int* in_sizes, int n_in,
                              void* d_out, int out_size, void* d_ws, size_t ws_size,
                              hipStream_t stream) {
    const float* s            = (const float*)d_in[0];
    const float* rot          = (const float*)d_in[1];
    const float* trans        = (const float*)d_in[2];
    const float* pair_mask    = (const float*)d_in[3];
    const float* w_q          = (const float*)d_in[4];
    const float* b_q          = (const float*)d_in[5];
    const float* w_kv         = (const float*)d_in[6];
    const float* b_kv         = (const float*)d_in[7];
    const float* w_qp         = (const float*)d_in[8];
    const float* b_qp         = (const float*)d_in[9];
    const float* w_kvp        = (const float*)d_in[10];
    const float* b_kvp        = (const float*)d_in[11];
    const float* head_weights = (const float*)d_in[12];
    const float* w_out        = (const float*)d_in[13];
    const float* b_out        = (const float*)d_in[14];
    float* out = (float*)d_out;
    float* ws  = (float*)d_ws;

    float*          PROJ = ws + OFF_PROJ;
    unsigned short* MBp  = (unsigned short*)(ws + OFF_MB);
    unsigned short* Og   = (unsigned short*)(ws + OFF_O);
    unsigned short* OPg  = (unsigned short*)(ws + OFF_OP);
    unsigned short* CAT  = (unsigned short*)(ws + OFF_CAT);
    unsigned short* Qf   = (unsigned short*)(ws + OFF_QF);
    unsigned short* Kf   = (unsigned short*)(ws + OFF_KF);
    unsigned short* Vt   = (unsigned short*)(ws + OFF_VT);

    // zero Vt (pad rows 40..63 must be 0 for the PV d-tile-1 MFMA)
    (void)hipMemsetAsync(ws + OFF_VT, 0, 589824 * sizeof(float), stream);
    proj_mfma<<<48 * 36, 64, 0, stream>>>(s, w_q, w_kv, w_qp, w_kvp,
                                          b_q, b_kv, b_qp, b_kvp, PROJ);
    pack2_kernel<<<B_ * N_, 256, 0, stream>>>(PROJ, rot, trans, head_weights,
                                              Qf, Kf, Vt);
    mb_pack<<<B_ * 24 * 24, 256, 0, stream>>>(pair_mask, MBp);   // after pack2: aliases PROJ
    attn2_kernel<<<B_ * H_ * 24, 512, 0, stream>>>(Qf, Kf, Vt, MBp, Og, OPg);
    cat_kernel<<<B_ * N_, 128, 0, stream>>>(Og, OPg, rot, trans, CAT);
    out_mfma<<<48 * 12, 64, 0, stream>>>(CAT, w_out, b_out, out);
}

// Round 6
// 77.664 us; speedup vs baseline: 7.3635x; 1.1113x over previous
//
#include <hip/hip_runtime.h>
#include <hip/hip_bf16.h>
#include <math.h>

typedef __attribute__((ext_vector_type(4)))  short short4v;
typedef __attribute__((ext_vector_type(8)))  short short8;
typedef __attribute__((ext_vector_type(16))) float f32x16;

#define B_   2
#define N_   768
#define CN_  384
#define H_   12
#define INF_ 100000.0f
#define EPS_ 1e-7f

// ---------------- workspace layout (f32-slot offsets) ----------------
// PROJ f32 [1536][1152] (bias-added GEMM out; dead after pack2) -- arena reused by:
//   Og  bf16 [1536][192]          at slot 589824  (147456 slots)
//   OPg bf16 [1536][288]          at slot 737280  (221184 slots)
//   CAT bf16 [1536][576]          at slot 958464  (442368 slots)
// Qf bf16 [24][768][32]  at 1769472
// Kf bf16 [24][768][32]  at 2064384
// Vt bf16 [24][64][768]  at 2359296   (rows 40..63 NEVER written: garbage is
//   provably confined to discarded acc1 regs 4..15 -- see attn2 merge, r<20)
// MB bf16 [2][24][24][64][16] at 2949120  (own region; no longer aliases PROJ)
#define OFF_PROJ 0
#define OFF_O    589824
#define OFF_OP   737280
#define OFF_CAT  958464
#define OFF_QF   1769472
#define OFF_KF   2064384
#define OFF_VT   2359296
#define OFF_MB   2949120

__device__ inline float b2f(unsigned short u) {
    union { unsigned int i; float f; } x; x.i = ((unsigned int)u) << 16; return x.f;
}
__device__ inline unsigned short f2b(float f) {
    __hip_bfloat16 h = __float2bfloat16(f);
    return *reinterpret_cast<unsigned short*>(&h);
}
__device__ inline short8 cvt8(float4 f0, float4 f1) {
    short8 r;
    r[0] = (short)f2b(f0.x); r[1] = (short)f2b(f0.y);
    r[2] = (short)f2b(f0.z); r[3] = (short)f2b(f0.w);
    r[4] = (short)f2b(f1.x); r[5] = (short)f2b(f1.y);
    r[6] = (short)f2b(f1.z); r[7] = (short)f2b(f1.w);
    return r;
}

// ============================================================
// fused: projection GEMM (MFMA, blocks 0..1727) + mask-bias pack (blocks 1728..2879)
// proj: one wave per 32x32 tile of proj[1536][1152] = S @ Wcat^T + bias
//   D: col = c0 + (lane&31), row = r0 + (reg&3)+8*(reg>>2)+4*(lane>>5)
// mb:   MB[b][it][jt][64][16], entry (l,reg) =
//   INF*(mask[b][i0+(l&31)][j0+(reg&3)+8*(reg>>2)+4*(l>>5)] - 1); thread t = l.
// ============================================================
__global__ __launch_bounds__(64) void proj_mb_kernel(
    const float* __restrict__ s,
    const float* __restrict__ w_q,  const float* __restrict__ w_kv,
    const float* __restrict__ w_qp, const float* __restrict__ w_kvp,
    const float* __restrict__ b_q,  const float* __restrict__ b_kv,
    const float* __restrict__ b_qp, const float* __restrict__ b_kvp,
    const float* __restrict__ mask,
    float* __restrict__ proj, unsigned short* __restrict__ MB)
{
    if (blockIdx.x >= 1728) {
        // ---- mask-bias pack ----
        const int tile = blockIdx.x - 1728;   // b*576 + it*24 + jt
        const int jt = tile % 24;
        const int it = (tile / 24) % 24;
        const int b  = tile / 576;
        const int tt = threadIdx.x;           // == l
        const int i0 = it * 32, j0 = jt * 32;
        const float* mrow = mask + ((long)b * N_ + i0 + (tt & 31)) * N_
                          + j0 + (tt >> 5) * 4;
        union { unsigned short u[16]; short8 v[2]; } o;
        #pragma unroll
        for (int g = 0; g < 4; ++g) {         // j-groups 0,8,16,24
            float4 mv = *(const float4*)(mrow + 8 * g);
            o.u[g*4+0] = f2b(INF_ * (mv.x - 1.f));
            o.u[g*4+1] = f2b(INF_ * (mv.y - 1.f));
            o.u[g*4+2] = f2b(INF_ * (mv.z - 1.f));
            o.u[g*4+3] = f2b(INF_ * (mv.w - 1.f));
        }
        unsigned short* outp = MB + (long)tile * 1024 + tt * 16;
        *(short8*)(outp)     = o.v[0];
        *(short8*)(outp + 8) = o.v[1];
        return;
    }
    // ---- projection GEMM ----
    const int tile = blockIdx.x;          // 48 * 36
    const int tn = tile % 36, tm = tile / 36;
    const int r0 = tm * 32, c0 = tn * 32;
    const int l  = threadIdx.x;
    const int li = l & 31, hf = l >> 5;

    const float* ap = s + (long)(r0 + li) * CN_ + hf * 8;
    const int col = c0 + li;
    const float* wb; float bias;
    if (col < 192)      { wb = w_q   + (long)col * CN_;        bias = b_q[col]; }
    else if (col < 576) { wb = w_kv  + (long)(col - 192) * CN_; bias = b_kv[col - 192]; }
    else if (col < 720) { wb = w_qp  + (long)(col - 576) * CN_; bias = b_qp[col - 576]; }
    else                { wb = w_kvp + (long)(col - 720) * CN_; bias = b_kvp[col - 720]; }
    wb += hf * 8;

    f32x16 acc = {};
    for (int k = 0; k < CN_; k += 32) {   // 2 MFMA per iter for ILP
        float4 a00 = *(const float4*)(ap + k);
        float4 a01 = *(const float4*)(ap + k + 4);
        float4 b00 = *(const float4*)(wb + k);
        float4 b01 = *(const float4*)(wb + k + 4);
        float4 a10 = *(const float4*)(ap + k + 16);
        float4 a11 = *(const float4*)(ap + k + 20);
        float4 b10 = *(const float4*)(wb + k + 16);
        float4 b11 = *(const float4*)(wb + k + 20);
        acc = __builtin_amdgcn_mfma_f32_32x32x16_bf16(cvt8(a00, a01), cvt8(b00, b01), acc, 0, 0, 0);
        acc = __builtin_amdgcn_mfma_f32_32x32x16_bf16(cvt8(a10, a11), cvt8(b10, b11), acc, 0, 0, 0);
    }
    #pragma unroll
    for (int r = 0; r < 16; ++r) {
        int row = r0 + (r & 3) + 8 * (r >> 2) + 4 * hf;
        proj[(long)row * 1152 + col] = acc[r] + bias;
    }
}

// ============================================================
// pack2: rotate/translate + scales -> bf16 frag-ready buffers (bias already in proj)
// Qf slots: [0:16) q/sqrt48, [16:28) hw*qp, 28=1, 29=1, 30,31=0
// Kf slots: [0:16) k, [16:28) kp, 28=kc_hi, 29=kc_lo, 30,31=0
// Vt[bh][d][n]: d 0..15 = v, 16..39 = vp  (40..63 left unwritten)
// ============================================================
__global__ __launch_bounds__(256) void pack2_kernel(
    const float* __restrict__ proj,
    const float* __restrict__ rot, const float* __restrict__ trans,
    const float* __restrict__ head_weights,
    unsigned short* __restrict__ Qf, unsigned short* __restrict__ Kf,
    unsigned short* __restrict__ Vt)
{
    __shared__ float raw[1152];
    __shared__ float pk[1152];
    __shared__ float rt[12];
    __shared__ float hws[12];
    __shared__ float kcs[12];
    const int bn = blockIdx.x;
    const int t  = threadIdx.x;
    const float* rowg = proj + (long)bn * 1152;
    for (int d = t; d < 288; d += 256)
        ((float4*)raw)[d] = ((const float4*)rowg)[d];
    if (t < 9) rt[t]     = rot[bn * 9 + t];
    if (t < 3) rt[9 + t] = trans[bn * 3 + t];
    if (t < 12) {
        float v  = head_weights[t];
        float sp = (v > 20.f) ? v : log1pf(expf(v));
        hws[t] = sp * 0.13608276348795434f;  // softplus * sqrt(1/54)
    }
    __syncthreads();
    // per-head layout: h*96 + [0:16)q [16:28)qp*hw [28:44)k [44:56)kp [56:72)v [72:96)vp
    for (int slot = t; slot < 1152; slot += 256) {
        int hh = slot / 96, o = slot - hh * 96;
        float val;
        if (o < 16) {
            val = raw[hh * 16 + o] * 0.144337567297406f;  // 1/sqrt(48)
        } else if (o < 28) {
            int c = o - 16, p = c / 3, x = c - p * 3;
            float r0 = raw[576 +      hh * 4 + p];
            float r1 = raw[576 + 48 + hh * 4 + p];
            float r2 = raw[576 + 96 + hh * 4 + p];
            val = (rt[x*3]*r0 + rt[x*3+1]*r1 + rt[x*3+2]*r2 + rt[9+x]) * hws[hh];
        } else if (o < 44) {
            val = raw[192 + hh * 32 + (o - 28)];
        } else if (o < 56) {
            int c = o - 44, p = c / 3, x = c - p * 3;
            float r0 = raw[720 +       hh * 12 + p];
            float r1 = raw[720 + 144 + hh * 12 + p];
            float r2 = raw[720 + 288 + hh * 12 + p];
            val = rt[x*3]*r0 + rt[x*3+1]*r1 + rt[x*3+2]*r2 + rt[9+x];
        } else if (o < 72) {
            val = raw[192 + hh * 32 + 16 + (o - 56)];
        } else {
            int c = o - 72, p = c / 3, x = c - p * 3;
            float r0 = raw[720 +       hh * 12 + 4 + p];
            float r1 = raw[720 + 144 + hh * 12 + 4 + p];
            float r2 = raw[720 + 288 + hh * 12 + 4 + p];
            val = rt[x*3]*r0 + rt[x*3+1]*r1 + rt[x*3+2]*r2 + rt[9+x];
        }
        pk[slot] = val;
    }
    __syncthreads();
    if (t < 12) {
        float s2 = 0.f;
        #pragma unroll
        for (int e = 0; e < 12; ++e) { float v = pk[t * 96 + 44 + e]; s2 += v * v; }
        kcs[t] = -0.5f * hws[t] * s2;
    }
    __syncthreads();
    const int b = bn / N_, n = bn % N_;
    for (int d = t; d < 384; d += 256) {
        int hh = d >> 5, slot = d & 31;
        long base = ((long)(b * H_ + hh) * N_ + n) * 32 + slot;
        float qv, kv;
        if (slot < 28)      qv = pk[hh * 96 + slot];
        else if (slot < 30) qv = 1.f;
        else                qv = 0.f;
        if (slot < 16)      kv = pk[hh * 96 + 28 + slot];
        else if (slot < 28) kv = pk[hh * 96 + 44 + (slot - 16)];
        else if (slot == 28) kv = b2f(f2b(kcs[hh]));
        else if (slot == 29) kv = kcs[hh] - b2f(f2b(kcs[hh]));
        else                kv = 0.f;
        Qf[base] = f2b(qv);
        Kf[base] = f2b(kv);
    }
    for (int d = t; d < 480; d += 256) {
        int hh = d / 40, dd = d - hh * 40;
        Vt[((long)(b * H_ + hh) * 64 + dd) * N_ + n] = f2b(pk[hh * 96 + 56 + dd]);
    }
}

// ============================================================
// MFMA flash attention. Grid (b*12+h)*24+it, 512 threads = 8 waves.
// Wave w sweeps j in [w*96, w*96+96). No LDS in main loop; merge at end.
// Vt rows 40..63 are uninitialized: they feed only acc1 regs 4..15,
// which are never stored (merge handles r<20; acc1 contributes r=16..19).
// ============================================================
__global__ __launch_bounds__(512) void attn2_kernel(
    const unsigned short* __restrict__ Qf, const unsigned short* __restrict__ Kf,
    const unsigned short* __restrict__ Vt, const unsigned short* __restrict__ MB,
    unsigned short* __restrict__ Og, unsigned short* __restrict__ OPg)
{
    __shared__ float red[8][64][22];
    const int blk = blockIdx.x;
    const int it = blk % 24;
    const int bh = blk / 24;
    const int hh = bh % 12;
    const int b  = bh / 12;
    const int t  = threadIdx.x;
    const int w  = t >> 6;
    const int l  = t & 63;
    const int li = l & 31;
    const int hf = l >> 5;
    const int i0 = it * 32;

    const unsigned short* qbase = Qf + ((long)bh * N_ + i0 + li) * 32 + hf * 8;
    short8 q0 = *(const short8*)(qbase);
    short8 q1 = *(const short8*)(qbase + 16);

    f32x16 acc0 = {};
    f32x16 acc1 = {};
    float m = -1e30f, lsum = 0.f;
    const unsigned short* vtb = Vt + (long)bh * 64 * N_;
    const unsigned short* mbb = MB + ((long)(b * 24 + it)) * 24 * 1024;

    for (int jt = w * 3; jt < w * 3 + 3; ++jt) {
        const int j0 = jt * 32;
        // C-init from mask-bias fragments
        const unsigned short* mbp = mbb + (long)jt * 1024 + l * 16;
        short8 mb0 = *(const short8*)(mbp);
        short8 mb1 = *(const short8*)(mbp + 8);
        f32x16 S;
        #pragma unroll
        for (int r = 0; r < 8; ++r) S[r]     = b2f((unsigned short)mb0[r]);
        #pragma unroll
        for (int r = 0; r < 8; ++r) S[8 + r] = b2f((unsigned short)mb1[r]);
        // K fragments (lane: j=li, k chunk hf*8; chunks k0..15 / k16..31)
        const unsigned short* kp = Kf + ((long)bh * N_ + j0 + li) * 32 + hf * 8;
        short8 k0 = *(const short8*)(kp);
        short8 k1 = *(const short8*)(kp + 16);
        // S^T[j][i] = sum_k K[j][k] Q[i][k]  (lane holds col i=li, 16 j rows)
        S = __builtin_amdgcn_mfma_f32_32x32x16_bf16(k0, q0, S, 0, 0, 0);
        S = __builtin_amdgcn_mfma_f32_32x32x16_bf16(k1, q1, S, 0, 0, 0);
        // online softmax for row i=li; halves exchange via permlane32_swap.
        float mloc = S[0];
        #pragma unroll
        for (int r = 1; r < 16; ++r) mloc = fmaxf(mloc, S[r]);
        {
            auto mm = __builtin_amdgcn_permlane32_swap(
                __float_as_int(mloc), __float_as_int(mloc), false, false);
            mloc = fmaxf(__int_as_float(mm[0]), __int_as_float(mm[1]));
        }
        float newm = fmaxf(m, mloc);
        float scale = __expf(m - newm);
        float ps = 0.f;
        f32x16 p;
        #pragma unroll
        for (int r = 0; r < 16; ++r) { p[r] = __expf(S[r] - newm); ps += p[r]; }
        {
            auto ss = __builtin_amdgcn_permlane32_swap(
                __float_as_int(ps), __float_as_int(ps), false, false);
            ps = __int_as_float(ss[0]) + __int_as_float(ss[1]);
        }
        lsum = lsum * scale + ps;
        m = newm;
        #pragma unroll
        for (int r = 0; r < 16; ++r) acc0[r] *= scale;
        #pragma unroll
        for (int r = 0; r < 4; ++r)  acc1[r] *= scale;
        // pack p -> PV B-fragments: lane's own cvt_pk words, in order.
        int c[8];
        #pragma unroll
        for (int r = 0; r < 8; ++r) {
            asm("v_cvt_pk_bf16_f32 %0, %1, %2" : "=v"(c[r]) : "v"(p[2*r]), "v"(p[2*r+1]));
        }
        union { int w4[4]; short8 v; } bf0, bf1;
        bf0.w4[0] = c[0]; bf0.w4[1] = c[1]; bf0.w4[2] = c[2]; bf0.w4[3] = c[3];
        bf1.w4[0] = c[4]; bf1.w4[1] = c[5]; bf1.w4[2] = c[6]; bf1.w4[3] = c[7];
        // V^T A-frags at the matching interleaved j offsets (two 8B loads each)
        union { short4v h[2]; short8 v; } v00, v01, v10, v11;
        const unsigned short* vr0 = vtb + (long)li * N_        + j0 + hf * 4;
        const unsigned short* vr1 = vtb + (long)(32 + li) * N_ + j0 + hf * 4;
        v00.h[0] = *(const short4v*)(vr0);       v00.h[1] = *(const short4v*)(vr0 + 8);
        v01.h[0] = *(const short4v*)(vr1);       v01.h[1] = *(const short4v*)(vr1 + 8);
        v10.h[0] = *(const short4v*)(vr0 + 16);  v10.h[1] = *(const short4v*)(vr0 + 24);
        v11.h[0] = *(const short4v*)(vr1 + 16);  v11.h[1] = *(const short4v*)(vr1 + 24);
        acc0 = __builtin_amdgcn_mfma_f32_32x32x16_bf16(v00.v, bf0.v, acc0, 0, 0, 0);
        acc1 = __builtin_amdgcn_mfma_f32_32x32x16_bf16(v01.v, bf0.v, acc1, 0, 0, 0);
        acc0 = __builtin_amdgcn_mfma_f32_32x32x16_bf16(v10.v, bf1.v, acc0, 0, 0, 0);
        acc1 = __builtin_amdgcn_mfma_f32_32x32x16_bf16(v11.v, bf1.v, acc1, 0, 0, 0);
    }
    // per-wave partials -> LDS
    float* rd = &red[w][l][0];
    rd[0] = m; rd[1] = lsum;
    #pragma unroll
    for (int r = 0; r < 16; ++r) rd[2 + r]  = acc0[r];
    #pragma unroll
    for (int r = 0; r < 4; ++r)  rd[18 + r] = acc1[r];
    __syncthreads();
    // merge 8 chunks: thread group g=t>>6 handles regs {g, g+8, g+16} of slot l2
    {
        const int l2 = t & 63, g = t >> 6;
        const int li2 = l2 & 31, hf2 = l2 >> 5;
        float ms = -1e30f;
        #pragma unroll
        for (int ww = 0; ww < 8; ++ww) ms = fmaxf(ms, red[ww][l2][0]);
        float wt[8]; float lf = 0.f;
        #pragma unroll
        for (int ww = 0; ww < 8; ++ww) {
            wt[ww] = __expf(red[ww][l2][0] - ms);
            lf += wt[ww] * red[ww][l2][1];
        }
        float inv = 1.f / lf;
        const int n = i0 + li2;
        #pragma unroll
        for (int rr = 0; rr < 3; ++rr) {
            int r = g + rr * 8;
            if (r < 20) {
                float v = 0.f;
                #pragma unroll
                for (int ww = 0; ww < 8; ++ww) v += wt[ww] * red[ww][l2][2 + r];
                v *= inv;
                int d = (r < 16) ? ((r & 3) + 8 * (r >> 2) + 4 * hf2)
                                 : (32 + (r - 16) + 4 * hf2);
                unsigned short ov = f2b(v);
                if (d < 16) Og [((long)(b * N_ + n)) * 192 + hh * 16 + d] = ov;
                else        OPg[((long)(b * N_ + n)) * 288 + hh * 24 + (d - 16)] = ov;
            }
        }
    }
}

// ============================================================
// cat build: inverse rotation + norms -> cat[1536][576] bf16
// ============================================================
__global__ __launch_bounds__(128) void cat_kernel(
    const unsigned short* __restrict__ Og, const unsigned short* __restrict__ OPg,
    const float* __restrict__ rot, const float* __restrict__ trans,
    unsigned short* __restrict__ catg)
{
    __shared__ float cat[576];
    __shared__ float rt[12];
    const int bn = blockIdx.x;
    const int t  = threadIdx.x;
    if (t < 9) rt[t]     = rot[bn * 9 + t];
    if (t < 3) rt[9 + t] = trans[bn * 3 + t];
    for (int d = t; d < 192; d += 128) cat[d] = b2f(Og[(long)bn * 192 + d]);
    __syncthreads();
    if (t < 96) {
        float g0 = b2f(OPg[(long)bn * 288 + t * 3 + 0]) - rt[9];
        float g1 = b2f(OPg[(long)bn * 288 + t * 3 + 1]) - rt[10];
        float g2 = b2f(OPg[(long)bn * 288 + t * 3 + 2]) - rt[11];
        float l0 = rt[0]*g0 + rt[3]*g1 + rt[6]*g2;
        float l1 = rt[1]*g0 + rt[4]*g1 + rt[7]*g2;
        float l2 = rt[2]*g0 + rt[5]*g1 + rt[8]*g2;
        cat[192 + t] = l0;
        cat[288 + t] = l1;
        cat[384 + t] = l2;
        cat[480 + t] = sqrtf(l0*l0 + l1*l1 + l2*l2 + EPS_);
    }
    __syncthreads();
    for (int d = t; d < 576; d += 128) catg[(long)bn * 576 + d] = f2b(cat[d]);
}

// ============================================================
// output GEMM (MFMA): out[1536][384] = cat(bf16) @ w_out^T + b_out
// one wave per 32x32 tile; w_out converted bf16 in-flight.
// ============================================================
__global__ __launch_bounds__(64) void out_mfma(
    const unsigned short* __restrict__ catg,  // [1536][576] bf16
    const float* __restrict__ w_out,          // [384][576]
    const float* __restrict__ b_out,
    float* __restrict__ out)
{
    const int tile = blockIdx.x;          // 48 * 12
    const int tn = tile % 12, tm = tile / 12;
    const int r0 = tm * 32, c0 = tn * 32;
    const int l  = threadIdx.x;
    const int li = l & 31, hf = l >> 5;

    const unsigned short* ap = catg + (long)(r0 + li) * 576 + hf * 8;
    const float* wp = w_out + (long)(c0 + li) * 576 + hf * 8;

    f32x16 acc = {};
    for (int k = 0; k < 576; k += 32) {   // 2 MFMA per iter
        short8 a0 = *(const short8*)(ap + k);
        short8 a1 = *(const short8*)(ap + k + 16);
        float4 b00 = *(const float4*)(wp + k);
        float4 b01 = *(const float4*)(wp + k + 4);
        float4 b10 = *(const float4*)(wp + k + 16);
        float4 b11 = *(const float4*)(wp + k + 20);
        acc = __builtin_amdgcn_mfma_f32_32x32x16_bf16(a0, cvt8(b00, b01), acc, 0, 0, 0);
        acc = __builtin_amdgcn_mfma_f32_32x32x16_bf16(a1, cvt8(b10, b11), acc, 0, 0, 0);
    }
    float bias = b_out[c0 + li];
    #pragma unroll
    for (int r = 0; r < 16; ++r) {
        int row = r0 + (r & 3) + 8 * (r >> 2) + 4 * hf;
        out[(long)row * 384 + c0 + li] = acc[r] + bias;
    }
}

// ============================================================
extern "C" void kernel_launch(void* const* d_in, const int* in_sizes, int n_in,
                              void* d_out, int out_size, void* d_ws, size_t ws_size,
                              hipStream_t stream) {
    const float* s            = (const float*)d_in[0];
    const float* rot          = (const float*)d_in[1];
    const float* trans        = (const float*)d_in[2];
    const float* pair_mask    = (const float*)d_in[3];
    const float* w_q          = (const float*)d_in[4];
    const float* b_q          = (const float*)d_in[5];
    const float* w_kv         = (const float*)d_in[6];
    const float* b_kv         = (const float*)d_in[7];
    const float* w_qp         = (const float*)d_in[8];
    const float* b_qp         = (const float*)d_in[9];
    const float* w_kvp        = (const float*)d_in[10];
    const float* b_kvp        = (const float*)d_in[11];
    const float* head_weights = (const float*)d_in[12];
    const float* w_out        = (const float*)d_in[13];
    const float* b_out        = (const float*)d_in[14];
    float* out = (float*)d_out;
    float* ws  = (float*)d_ws;

    float*          PROJ = ws + OFF_PROJ;
    unsigned short* Og   = (unsigned short*)(ws + OFF_O);
    unsigned short* OPg  = (unsigned short*)(ws + OFF_OP);
    unsigned short* CAT  = (unsigned short*)(ws + OFF_CAT);
    unsigned short* Qf   = (unsigned short*)(ws + OFF_QF);
    unsigned short* Kf   = (unsigned short*)(ws + OFF_KF);
    unsigned short* Vt   = (unsigned short*)(ws + OFF_VT);
    unsigned short* MBp  = (unsigned short*)(ws + OFF_MB);

    proj_mb_kernel<<<48 * 36 + B_ * 24 * 24, 64, 0, stream>>>(
        s, w_q, w_kv, w_qp, w_kvp, b_q, b_kv, b_qp, b_kvp, pair_mask, PROJ, MBp);
    pack2_kernel<<<B_ * N_, 256, 0, stream>>>(PROJ, rot, trans, head_weights,
                                              Qf, Kf, Vt);
    attn2_kernel<<<B_ * H_ * 24, 512, 0, stream>>>(Qf, Kf, Vt, MBp, Og, OPg);
    cat_kernel<<<B_ * N_, 128, 0, stream>>>(Og, OPg, rot, trans, CAT);
    out_mfma<<<48 * 12, 64, 0, stream>>>(CAT, w_out, b_out, out);
}